// Round 1
// baseline (1380.928 us; speedup 1.0000x reference)
//
#include <hip/hip_runtime.h>
#include <hip/hip_bf16.h>
#include <cstdint>
#include <cstddef>

#define D_MODEL 4096
#define D_LATENT 512
#define NUM_HEADS 32
#define HEAD_DIM 128
#define BATCH 2
#define SEQ 2048
#define ROWS (BATCH*SEQ)   // 4096

typedef __attribute__((ext_vector_type(8))) short bf16x8;
typedef __attribute__((ext_vector_type(4))) float f32x4;

static __device__ __forceinline__ unsigned short f2bf(float f){
  union { float f; uint32_t u; } v; v.f = f;
  uint32_t r = (v.u + 0x7fffu + ((v.u >> 16) & 1u)) >> 16;
  return (unsigned short)r;
}
static __device__ __forceinline__ float bf2f(unsigned short h){
  union { uint32_t u; float f; } v; v.u = ((uint32_t)h) << 16;
  return v.f;
}

// ---------------------------------------------------------------------------
// W [K][N] f32 (row-major) -> Wt [N][K] bf16 (row-major). 64x64 tiles.
// ---------------------------------------------------------------------------
__global__ __launch_bounds__(256) void transpose_convert(
    const float* __restrict__ W, unsigned short* __restrict__ Wt, int K, int N){
  __shared__ float tile[64][65];
  const int k0 = blockIdx.x * 64, n0 = blockIdx.y * 64;
  const int t = threadIdx.x;
  #pragma unroll
  for (int j = 0; j < 16; ++j){
    const int idx = t + 256*j;
    const int r = idx >> 6, c = idx & 63;
    tile[r][c] = W[(size_t)(k0 + r) * N + n0 + c];
  }
  __syncthreads();
  #pragma unroll
  for (int j = 0; j < 16; ++j){
    const int idx = t + 256*j;
    const int r = idx >> 6, c = idx & 63;   // r: n-local, c: k-local
    Wt[(size_t)(n0 + r) * K + k0 + c] = f2bf(tile[c][r]);
  }
}

// ---------------------------------------------------------------------------
// RoPE cos/sin tables: [SEQ][64] f32 each.
// ---------------------------------------------------------------------------
__global__ __launch_bounds__(256) void rope_table_kernel(float* __restrict__ ct,
                                                         float* __restrict__ st){
  const int i = blockIdx.x * 256 + threadIdx.x;
  if (i >= SEQ * 64) return;
  const int s = i >> 6, j = i & 63;
  const float inv = powf(10000.0f, -(float)j / 64.0f);
  const double a = (double)s * (double)inv;
  ct[i] = (float)cos(a);
  st[i] = (float)sin(a);
}

// ---------------------------------------------------------------------------
// In-place RoPE on bf16 buffer [ROWS][D_MODEL] viewed as [ROWS][H][128].
// ---------------------------------------------------------------------------
__global__ __launch_bounds__(256) void rope_apply(unsigned short* __restrict__ buf,
    const float* __restrict__ ct, const float* __restrict__ st){
  const int i = blockIdx.x * 256 + threadIdx.x;  // ROWS*32*64 total
  const int j = i & 63;
  const int tmp = i >> 6;
  const int h = tmp & 31;
  const int row = tmp >> 5;
  const int s = row & (SEQ - 1);
  const float c = ct[s*64 + j], sn = st[s*64 + j];
  const size_t base = (size_t)row * D_MODEL + (size_t)h * 128;
  const float x1 = bf2f(buf[base + j]);
  const float x2 = bf2f(buf[base + j + 64]);
  buf[base + j]      = f2bf(x1 * c - x2 * sn);
  buf[base + j + 64] = f2bf(x2 * c + x1 * sn);
}

// ---------------------------------------------------------------------------
// GEMM: C[M][N] = A[M][K] * Bt[N][K]^T.  A: f32 or bf16 (AF32). C: f32 or bf16.
// 128x128 tile, BK=64, 256 threads = 4 waves (2x2), 4x4 16x16x32 frags/wave.
// LDS tiles [128 rows][64 cols bf16] with XOR-swizzle: 16B chunk ^= (row&7).
// ---------------------------------------------------------------------------
template<bool AF32, bool OF32>
__global__ __launch_bounds__(256) void gemm_kernel(
    const void* __restrict__ Ap, const unsigned short* __restrict__ Bt,
    void* __restrict__ Cp, int M, int N, int K){
  __shared__ __align__(16) char As[128 * 128];
  __shared__ __align__(16) char Bs[128 * 128];
  const int t = threadIdx.x;
  const int m0 = blockIdx.y * 128, n0 = blockIdx.x * 128;
  const int l = t & 63, wid = t >> 6;
  const int wr = wid >> 1, wcn = wid & 1;
  const int lr = l & 15, lg = l >> 4;
  f32x4 acc[4][4];
  #pragma unroll
  for (int i = 0; i < 4; ++i)
    #pragma unroll
    for (int j = 0; j < 4; ++j)
      #pragma unroll
      for (int r = 0; r < 4; ++r) acc[i][j][r] = 0.0f;

  const int rowB = t >> 3;   // 0..31
  const int chunk = t & 7;   // 16B chunk within 128B row
  const int kTiles = K >> 6;

  for (int kt = 0; kt < kTiles; ++kt){
    const int k0 = kt << 6;
    #pragma unroll
    for (int j = 0; j < 4; ++j){
      const int row = rowB + 32*j;
      uint4 da;
      if constexpr (AF32){
        const float* ap = (const float*)Ap + (size_t)(m0 + row) * K + k0 + chunk*8;
        const float4 lo = *(const float4*)ap;
        const float4 hi = *(const float4*)(ap + 4);
        unsigned short* dp = (unsigned short*)&da;
        dp[0]=f2bf(lo.x); dp[1]=f2bf(lo.y); dp[2]=f2bf(lo.z); dp[3]=f2bf(lo.w);
        dp[4]=f2bf(hi.x); dp[5]=f2bf(hi.y); dp[6]=f2bf(hi.z); dp[7]=f2bf(hi.w);
      } else {
        da = *(const uint4*)((const unsigned short*)Ap + (size_t)(m0 + row) * K + k0 + chunk*8);
      }
      *(uint4*)(As + row*128 + ((chunk ^ (row & 7)) * 16)) = da;
      const uint4 db = *(const uint4*)(Bt + (size_t)(n0 + row) * K + k0 + chunk*8);
      *(uint4*)(Bs + row*128 + ((chunk ^ (row & 7)) * 16)) = db;
    }
    __syncthreads();
    #pragma unroll
    for (int kc = 0; kc < 2; ++kc){
      bf16x8 af[4], bfv[4];
      const int ch = kc*4 + lg;
      #pragma unroll
      for (int mb = 0; mb < 4; ++mb){
        const int row = wr*64 + mb*16 + lr;
        af[mb] = *(const bf16x8*)(As + row*128 + ((ch ^ (row & 7)) * 16));
      }
      #pragma unroll
      for (int nb = 0; nb < 4; ++nb){
        const int row = wcn*64 + nb*16 + lr;
        bfv[nb] = *(const bf16x8*)(Bs + row*128 + ((ch ^ (row & 7)) * 16));
      }
      #pragma unroll
      for (int mb = 0; mb < 4; ++mb)
        #pragma unroll
        for (int nb = 0; nb < 4; ++nb)
          acc[mb][nb] = __builtin_amdgcn_mfma_f32_16x16x32_bf16(af[mb], bfv[nb], acc[mb][nb], 0, 0, 0);
    }
    __syncthreads();
  }
  #pragma unroll
  for (int mb = 0; mb < 4; ++mb)
    #pragma unroll
    for (int nb = 0; nb < 4; ++nb)
      #pragma unroll
      for (int r = 0; r < 4; ++r){
        const int row = m0 + wr*64 + mb*16 + lg*4 + r;
        const int col = n0 + wcn*64 + nb*16 + lr;
        if constexpr (OF32) ((float*)Cp)[(size_t)row * N + col] = acc[mb][nb][r];
        else ((unsigned short*)Cp)[(size_t)row * N + col] = f2bf(acc[mb][nb][r]);
      }
}

// ---------------------------------------------------------------------------
// Flash attention, no mask. Grid (SEQ/64, B*H). 256 thr = 4 waves, each wave
// owns 16 q-rows. KBLK=64. K-tile [64][128] and V^T-tile [128][64] staged in
// swizzled LDS. Online softmax via 16-lane shfl_xor reductions. P goes
// through wave-private LDS to re-layout C-frag -> A-frag.
// ---------------------------------------------------------------------------
__global__ __launch_bounds__(256) void attn_kernel(
    const unsigned short* __restrict__ q, const unsigned short* __restrict__ kp,
    const unsigned short* __restrict__ vp, unsigned short* __restrict__ o){
  __shared__ __align__(16) char Ks[64 * 256];    // 16 KB
  __shared__ __align__(16) char Vt[128 * 128];   // 16 KB
  __shared__ __align__(16) char Pl[4 * 2048];    // 8 KB, wave-private slabs
  const int t = threadIdx.x;
  const int l = t & 63, w = t >> 6;
  const int lr = l & 15, lg = l >> 4;
  const int qb = blockIdx.x;
  const int bh = blockIdx.y;
  const int b = bh >> 5, h = bh & 31;
  const size_t qrow0 = (size_t)b * SEQ + qb*64 + w*16;
  const size_t cb = (size_t)h * 128;
  char* Pw = Pl + w * 2048;

  bf16x8 qf[4];
  #pragma unroll
  for (int kc = 0; kc < 4; ++kc)
    qf[kc] = *(const bf16x8*)(q + (qrow0 + lr) * D_MODEL + cb + kc*32 + lg*8);

  float m_[4], l_[4];
  f32x4 accv[8];
  #pragma unroll
  for (int r = 0; r < 4; ++r){ m_[r] = -1e30f; l_[r] = 0.0f; }
  #pragma unroll
  for (int nb = 0; nb < 8; ++nb)
    #pragma unroll
    for (int r = 0; r < 4; ++r) accv[nb][r] = 0.0f;

  const float scale = 0.08838834764831845f;  // 1/sqrt(128)

  for (int kb = 0; kb < SEQ/64; ++kb){
    const size_t kr0 = (size_t)b * SEQ + kb*64;
    // stage K [64 keys][128 d] and V^T [128 d][64 keys]
    #pragma unroll
    for (int j = 0; j < 4; ++j){
      const int idx = t + 256*j;
      const int r = idx >> 4, ch = idx & 15;
      const uint4 dk = *(const uint4*)(kp + (kr0 + r) * D_MODEL + cb + ch*8);
      *(uint4*)(Ks + r*256 + ((ch ^ (r & 7)) * 16)) = dk;
      const uint4 dv = *(const uint4*)(vp + (kr0 + r) * D_MODEL + cb + ch*8);
      const unsigned short* pv = (const unsigned short*)&dv;
      #pragma unroll
      for (int e = 0; e < 8; ++e){
        const int d = ch*8 + e;
        *(unsigned short*)(Vt + d*128 + (((r >> 3) ^ (d & 7)) * 16) + (r & 7)*2) = pv[e];
      }
    }
    __syncthreads();
    // scores = Q(16x128) @ K^T(128x64)
    f32x4 sc[4];
    #pragma unroll
    for (int nb = 0; nb < 4; ++nb)
      #pragma unroll
      for (int r = 0; r < 4; ++r) sc[nb][r] = 0.0f;
    #pragma unroll
    for (int kc = 0; kc < 4; ++kc){
      const int ch = kc*4 + lg;
      #pragma unroll
      for (int nb = 0; nb < 4; ++nb){
        const int row = nb*16 + lr;
        const bf16x8 kf = *(const bf16x8*)(Ks + row*256 + ((ch ^ (row & 7)) * 16));
        sc[nb] = __builtin_amdgcn_mfma_f32_16x16x32_bf16(qf[kc], kf, sc[nb], 0, 0, 0);
      }
    }
    // online softmax (rows owned in C-layout: row = lg*4 + r)
    float p[4][4];
    #pragma unroll
    for (int r = 0; r < 4; ++r){
      float mx = fmaxf(fmaxf(sc[0][r], sc[1][r]), fmaxf(sc[2][r], sc[3][r]));
      mx *= scale;
      mx = fmaxf(mx, __shfl_xor(mx, 1));
      mx = fmaxf(mx, __shfl_xor(mx, 2));
      mx = fmaxf(mx, __shfl_xor(mx, 4));
      mx = fmaxf(mx, __shfl_xor(mx, 8));
      const float mnew = fmaxf(m_[r], mx);
      const float al = __expf(m_[r] - mnew);
      float sum = 0.0f;
      #pragma unroll
      for (int nb = 0; nb < 4; ++nb){
        const float pe = __expf(sc[nb][r] * scale - mnew);
        p[r][nb] = pe; sum += pe;
      }
      sum += __shfl_xor(sum, 1);
      sum += __shfl_xor(sum, 2);
      sum += __shfl_xor(sum, 4);
      sum += __shfl_xor(sum, 8);
      l_[r] = l_[r] * al + sum;
      m_[r] = mnew;
      #pragma unroll
      for (int nb = 0; nb < 8; ++nb) accv[nb][r] *= al;
    }
    // P (C-layout) -> wave-private LDS (A-layout source)
    #pragma unroll
    for (int r = 0; r < 4; ++r){
      const int prow = lg*4 + r;
      #pragma unroll
      for (int nb = 0; nb < 4; ++nb){
        const int col = lr + nb*16;
        *(unsigned short*)(Pw + prow*128 + (((col >> 3) ^ (prow & 7)) * 16) + (col & 7)*2) = f2bf(p[r][nb]);
      }
    }
    __syncthreads();
    // O += P(16x64) @ V(64x128)
    #pragma unroll
    for (int kc = 0; kc < 2; ++kc){
      const int pch = kc*4 + lg;
      const bf16x8 pf = *(const bf16x8*)(Pw + lr*128 + ((pch ^ (lr & 7)) * 16));
      #pragma unroll
      for (int nb = 0; nb < 8; ++nb){
        const int vrow = nb*16 + lr;
        const bf16x8 vf = *(const bf16x8*)(Vt + vrow*128 + ((pch ^ (vrow & 7)) * 16));
        accv[nb] = __builtin_amdgcn_mfma_f32_16x16x32_bf16(pf, vf, accv[nb], 0, 0, 0);
      }
    }
    __syncthreads();
  }
  float rinv[4];
  #pragma unroll
  for (int r = 0; r < 4; ++r) rinv[r] = 1.0f / l_[r];
  #pragma unroll
  for (int nb = 0; nb < 8; ++nb)
    #pragma unroll
    for (int r = 0; r < 4; ++r)
      o[(qrow0 + lg*4 + r) * D_MODEL + cb + nb*16 + lr] = f2bf(accv[nb][r] * rinv[r]);
}

// ---------------------------------------------------------------------------
extern "C" void kernel_launch(void* const* d_in, const int* in_sizes, int n_in,
                              void* d_out, int out_size, void* d_ws, size_t ws_size,
                              hipStream_t stream){
  const float* hidden = (const float*)d_in[0];
  const float* Wq = (const float*)d_in[1];
  const float* Wc = (const float*)d_in[2];
  const float* Wk = (const float*)d_in[3];
  const float* Wv = (const float*)d_in[4];
  const float* Wo = (const float*)d_in[5];
  float* out = (float*)d_out;

  char* ws = (char*)d_ws;
  size_t off = 0;
  auto alloc = [&](size_t bytes)->char*{
    char* p = ws + off; off += (bytes + 255) & ~(size_t)255; return p;
  };
  unsigned short* Wqt  = (unsigned short*)alloc((size_t)D_MODEL * D_MODEL * 2);   // [4096][4096]
  unsigned short* Wct  = (unsigned short*)alloc((size_t)D_LATENT * D_MODEL * 2);  // [512][4096]
  unsigned short* Wkt  = (unsigned short*)alloc((size_t)D_MODEL * D_LATENT * 2);  // [4096][512]
  unsigned short* Wvt  = (unsigned short*)alloc((size_t)D_MODEL * D_LATENT * 2);  // [4096][512]
  unsigned short* Wot  = (unsigned short*)alloc((size_t)D_MODEL * D_MODEL * 2);   // [4096][4096]
  unsigned short* latent = (unsigned short*)alloc((size_t)ROWS * D_LATENT * 2);   // [4096][512]
  unsigned short* qbuf = (unsigned short*)alloc((size_t)ROWS * D_MODEL * 2);
  unsigned short* kbuf = (unsigned short*)alloc((size_t)ROWS * D_MODEL * 2);
  unsigned short* vbuf = (unsigned short*)alloc((size_t)ROWS * D_MODEL * 2);
  unsigned short* attnb= (unsigned short*)alloc((size_t)ROWS * D_MODEL * 2);
  float* ctab = (float*)alloc((size_t)SEQ * 64 * 4);
  float* stab = (float*)alloc((size_t)SEQ * 64 * 4);

  const dim3 B256(256);
  // weight transposes + bf16 conversion
  transpose_convert<<<dim3(64, 64), B256, 0, stream>>>(Wq, Wqt, D_MODEL, D_MODEL);
  transpose_convert<<<dim3(64, 8),  B256, 0, stream>>>(Wc, Wct, D_MODEL, D_LATENT);
  transpose_convert<<<dim3(8, 64),  B256, 0, stream>>>(Wk, Wkt, D_LATENT, D_MODEL);
  transpose_convert<<<dim3(8, 64),  B256, 0, stream>>>(Wv, Wvt, D_LATENT, D_MODEL);
  transpose_convert<<<dim3(64, 64), B256, 0, stream>>>(Wo, Wot, D_MODEL, D_MODEL);
  rope_table_kernel<<<512, B256, 0, stream>>>(ctab, stab);

  // projections
  gemm_kernel<true,  false><<<dim3(D_LATENT/128, ROWS/128), B256, 0, stream>>>(hidden, Wct, latent, ROWS, D_LATENT, D_MODEL);
  gemm_kernel<true,  false><<<dim3(D_MODEL/128,  ROWS/128), B256, 0, stream>>>(hidden, Wqt, qbuf,   ROWS, D_MODEL, D_MODEL);
  gemm_kernel<false, false><<<dim3(D_MODEL/128,  ROWS/128), B256, 0, stream>>>(latent, Wkt, kbuf,   ROWS, D_MODEL, D_LATENT);
  gemm_kernel<false, false><<<dim3(D_MODEL/128,  ROWS/128), B256, 0, stream>>>(latent, Wvt, vbuf,   ROWS, D_MODEL, D_LATENT);

  // RoPE on q and k
  rope_apply<<<(ROWS * NUM_HEADS * 64) / 256, B256, 0, stream>>>(qbuf, ctab, stab);
  rope_apply<<<(ROWS * NUM_HEADS * 64) / 256, B256, 0, stream>>>(kbuf, ctab, stab);

  // attention
  attn_kernel<<<dim3(SEQ/64, BATCH * NUM_HEADS), B256, 0, stream>>>(qbuf, kbuf, vbuf, attnb);

  // output projection (f32 out)
  gemm_kernel<false, true><<<dim3(D_MODEL/128, ROWS/128), B256, 0, stream>>>(attnb, Wot, out, ROWS, D_MODEL, D_MODEL);
}

// Round 2
// 864.978 us; speedup vs baseline: 1.5965x; 1.5965x over previous
//
#include <hip/hip_runtime.h>
#include <hip/hip_bf16.h>
#include <cstdint>
#include <cstddef>

#define D_MODEL 4096
#define D_LATENT 512
#define NUM_HEADS 32
#define HEAD_DIM 128
#define BATCH 2
#define SEQ 2048
#define ROWS (BATCH*SEQ)   // 4096

typedef __attribute__((ext_vector_type(8))) short bf16x8;
typedef __attribute__((ext_vector_type(4))) float f32x4;
typedef __attribute__((ext_vector_type(16))) float f32x16;
typedef unsigned int uint;

static __device__ __forceinline__ unsigned short f2bf(float f){
  union { float f; uint32_t u; } v; v.f = f;
  uint32_t r = (v.u + 0x7fffu + ((v.u >> 16) & 1u)) >> 16;
  return (unsigned short)r;
}
static __device__ __forceinline__ float bf2f(unsigned short h){
  union { uint32_t u; float f; } v; v.u = ((uint32_t)h) << 16;
  return v.f;
}
static __device__ __forceinline__ uint pk2(float lo, float hi2){
  return (uint)f2bf(lo) | ((uint)f2bf(hi2) << 16);
}

// ---------------------------------------------------------------------------
// W [K][N] f32 (row-major) -> Wt [N][K] bf16 (row-major). 64x64 tiles.
// ---------------------------------------------------------------------------
__global__ __launch_bounds__(256) void transpose_convert(
    const float* __restrict__ W, unsigned short* __restrict__ Wt, int K, int N){
  __shared__ float tile[64][65];
  const int k0 = blockIdx.x * 64, n0 = blockIdx.y * 64;
  const int t = threadIdx.x;
  #pragma unroll
  for (int j = 0; j < 16; ++j){
    const int idx = t + 256*j;
    const int r = idx >> 6, c = idx & 63;
    tile[r][c] = W[(size_t)(k0 + r) * N + n0 + c];
  }
  __syncthreads();
  #pragma unroll
  for (int j = 0; j < 16; ++j){
    const int idx = t + 256*j;
    const int r = idx >> 6, c = idx & 63;   // r: n-local, c: k-local
    Wt[(size_t)(n0 + r) * K + k0 + c] = f2bf(tile[c][r]);
  }
}

// ---------------------------------------------------------------------------
// V [ROWS][D_MODEL] bf16 (row = b*SEQ+s, col = h*128+d) ->
// Vt [B*H][128][SEQ]  (vt[bh][d][s])
// ---------------------------------------------------------------------------
__global__ __launch_bounds__(256) void v_transpose(
    const unsigned short* __restrict__ v, unsigned short* __restrict__ vt){
  __shared__ unsigned short tile[64][72];
  const int s0 = blockIdx.x * 64, d0 = blockIdx.y * 64, bh = blockIdx.z;
  const int b = bh >> 5, h = bh & 31;
  const int t = threadIdx.x;
  #pragma unroll
  for (int j = 0; j < 2; ++j){
    const int idx = t + 256*j;
    const int r = idx >> 3, ch = idx & 7;  // r: s-local, ch: 8-short chunk of d
    *(uint4*)&tile[r][ch*8] =
      *(const uint4*)&v[(size_t)(b*SEQ + s0 + r) * D_MODEL + h*128 + d0 + ch*8];
  }
  __syncthreads();
  #pragma unroll
  for (int j = 0; j < 16; ++j){
    const int idx = t + 256*j;
    const int r = idx >> 6, c = idx & 63;  // r: d-local, c: s-local
    vt[((size_t)bh*128 + d0 + r) * SEQ + s0 + c] = tile[c][r];
  }
}

// ---------------------------------------------------------------------------
// RoPE cos/sin tables: [SEQ][64] f32 each.
// ---------------------------------------------------------------------------
__global__ __launch_bounds__(256) void rope_table_kernel(float* __restrict__ ct,
                                                         float* __restrict__ st){
  const int i = blockIdx.x * 256 + threadIdx.x;
  if (i >= SEQ * 64) return;
  const int s = i >> 6, j = i & 63;
  const float inv = powf(10000.0f, -(float)j / 64.0f);
  const double a = (double)s * (double)inv;
  ct[i] = (float)cos(a);
  st[i] = (float)sin(a);
}

// ---------------------------------------------------------------------------
// In-place RoPE on bf16 buffer [ROWS][D_MODEL] viewed as [ROWS][H][128].
// Multiplies by `scale` (used to fold 1/sqrt(Dh) into Q).
// ---------------------------------------------------------------------------
__global__ __launch_bounds__(256) void rope_apply(unsigned short* __restrict__ buf,
    const float* __restrict__ ct, const float* __restrict__ st, float scale){
  const int i = blockIdx.x * 256 + threadIdx.x;  // ROWS*32*64 total
  const int j = i & 63;
  const int tmp = i >> 6;
  const int h = tmp & 31;
  const int row = tmp >> 5;
  const int s = row & (SEQ - 1);
  const float c = ct[s*64 + j], sn = st[s*64 + j];
  const size_t base = (size_t)row * D_MODEL + (size_t)h * 128;
  const float x1 = bf2f(buf[base + j]);
  const float x2 = bf2f(buf[base + j + 64]);
  buf[base + j]      = f2bf((x1 * c - x2 * sn) * scale);
  buf[base + j + 64] = f2bf((x2 * c + x1 * sn) * scale);
}

// ---------------------------------------------------------------------------
// GEMM: C[M][N] = A[M][K] * Bt[N][K]^T.  A: f32 or bf16 (AF32). C: f32 or bf16.
// 128x128 tile, BK=64, 256 threads = 4 waves (2x2), 4x4 16x16x32 frags/wave.
// ---------------------------------------------------------------------------
template<bool AF32, bool OF32>
__global__ __launch_bounds__(256) void gemm_kernel(
    const void* __restrict__ Ap, const unsigned short* __restrict__ Bt,
    void* __restrict__ Cp, int M, int N, int K){
  __shared__ __align__(16) char As[128 * 128];
  __shared__ __align__(16) char Bs[128 * 128];
  const int t = threadIdx.x;
  const int m0 = blockIdx.y * 128, n0 = blockIdx.x * 128;
  const int l = t & 63, wid = t >> 6;
  const int wr = wid >> 1, wcn = wid & 1;
  const int lr = l & 15, lg = l >> 4;
  f32x4 acc[4][4];
  #pragma unroll
  for (int i = 0; i < 4; ++i)
    #pragma unroll
    for (int j = 0; j < 4; ++j)
      #pragma unroll
      for (int r = 0; r < 4; ++r) acc[i][j][r] = 0.0f;

  const int rowB = t >> 3;
  const int chunk = t & 7;
  const int kTiles = K >> 6;

  for (int kt = 0; kt < kTiles; ++kt){
    const int k0 = kt << 6;
    #pragma unroll
    for (int j = 0; j < 4; ++j){
      const int row = rowB + 32*j;
      uint4 da;
      if constexpr (AF32){
        const float* ap = (const float*)Ap + (size_t)(m0 + row) * K + k0 + chunk*8;
        const float4 lo = *(const float4*)ap;
        const float4 hi = *(const float4*)(ap + 4);
        unsigned short* dp = (unsigned short*)&da;
        dp[0]=f2bf(lo.x); dp[1]=f2bf(lo.y); dp[2]=f2bf(lo.z); dp[3]=f2bf(lo.w);
        dp[4]=f2bf(hi.x); dp[5]=f2bf(hi.y); dp[6]=f2bf(hi.z); dp[7]=f2bf(hi.w);
      } else {
        da = *(const uint4*)((const unsigned short*)Ap + (size_t)(m0 + row) * K + k0 + chunk*8);
      }
      *(uint4*)(As + row*128 + ((chunk ^ (row & 7)) * 16)) = da;
      const uint4 db = *(const uint4*)(Bt + (size_t)(n0 + row) * K + k0 + chunk*8);
      *(uint4*)(Bs + row*128 + ((chunk ^ (row & 7)) * 16)) = db;
    }
    __syncthreads();
    #pragma unroll
    for (int kc = 0; kc < 2; ++kc){
      bf16x8 af[4], bfv[4];
      const int ch = kc*4 + lg;
      #pragma unroll
      for (int mb = 0; mb < 4; ++mb){
        const int row = wr*64 + mb*16 + lr;
        af[mb] = *(const bf16x8*)(As + row*128 + ((ch ^ (row & 7)) * 16));
      }
      #pragma unroll
      for (int nb = 0; nb < 4; ++nb){
        const int row = wcn*64 + nb*16 + lr;
        bfv[nb] = *(const bf16x8*)(Bs + row*128 + ((ch ^ (row & 7)) * 16));
      }
      #pragma unroll
      for (int mb = 0; mb < 4; ++mb)
        #pragma unroll
        for (int nb = 0; nb < 4; ++nb)
          acc[mb][nb] = __builtin_amdgcn_mfma_f32_16x16x32_bf16(af[mb], bfv[nb], acc[mb][nb], 0, 0, 0);
    }
    __syncthreads();
  }
  #pragma unroll
  for (int mb = 0; mb < 4; ++mb)
    #pragma unroll
    for (int nb = 0; nb < 4; ++nb)
      #pragma unroll
      for (int r = 0; r < 4; ++r){
        const int row = m0 + wr*64 + mb*16 + lg*4 + r;
        const int col = n0 + wcn*64 + nb*16 + lr;
        if constexpr (OF32) ((float*)Cp)[(size_t)row * N + col] = acc[mb][nb][r];
        else ((unsigned short*)Cp)[(size_t)row * N + col] = f2bf(acc[mb][nb][r]);
      }
}

// ---------------------------------------------------------------------------
// Flash attention, 8 waves x 32 q-rows (QBLK=256), KVBLK=64, 32x32x16 MFMA.
// Swapped QK^T (S^T = K*Q^T) so each lane holds P column-local; in-register
// softmax + P repack (pack pairs + cross-half shfl_xor). K [64][128] and
// V^T [128][64] staged via uint4 into XOR-swizzled LDS. Defer-max (THR=8).
// Q pre-scaled by 1/sqrt(Dh) at RoPE time.
// ---------------------------------------------------------------------------
__global__ __launch_bounds__(512) void attn_kernel(
    const unsigned short* __restrict__ q, const unsigned short* __restrict__ kp,
    const unsigned short* __restrict__ vt, unsigned short* __restrict__ o){
  __shared__ __align__(16) char Ks[64 * 256];    // 16 KB
  __shared__ __align__(16) char Vs[128 * 128];   // 16 KB
  const int t = threadIdx.x;
  const int l = t & 63, w = t >> 6;
  const int lq = l & 31, hi = l >> 5;
  const int qb = blockIdx.x, bh = blockIdx.y;
  const int b = bh >> 5;
  const size_t qbase = (size_t)b * SEQ + qb*256 + w*32;
  const size_t cb = (size_t)(bh & 31) * 128;

  // Q fragments: lane holds Q[qbase+lq][dc*16 + hi*8 .. +8]
  bf16x8 qf[8];
  #pragma unroll
  for (int dc = 0; dc < 8; ++dc)
    qf[dc] = *(const bf16x8*)(q + (qbase + lq) * D_MODEL + cb + dc*16 + hi*8);

  f32x16 O[4];
  #pragma unroll
  for (int nb = 0; nb < 4; ++nb)
    #pragma unroll
    for (int r = 0; r < 16; ++r) O[nb][r] = 0.0f;
  float m = -1e30f, lsum = 0.0f;

  for (int kb = 0; kb < SEQ/64; ++kb){
    const size_t kr0 = (size_t)b * SEQ + kb*64;
    // stage K tile [64 keys][128 d] (16 chunks/row) and V^T tile [128 d][64 s]
    #pragma unroll
    for (int j = 0; j < 2; ++j){
      const int idx = t + 512*j;
      { const int r = idx >> 4, ch = idx & 15;
        *(uint4*)(Ks + r*256 + ((ch ^ (r & 7)) * 16)) =
          *(const uint4*)(kp + (kr0 + r) * D_MODEL + cb + ch*8); }
      { const int r = idx >> 3, ch = idx & 7;
        *(uint4*)(Vs + r*128 + ((ch ^ (r & 7)) * 16)) =
          *(const uint4*)(vt + ((size_t)bh*128 + r) * SEQ + kb*64 + ch*8); }
    }
    __syncthreads();

    // S^T = K * Q^T : two 32-k blocks, accumulate over 8 d-chunks
    f32x16 s0, s1;
    #pragma unroll
    for (int r = 0; r < 16; ++r){ s0[r] = 0.0f; s1[r] = 0.0f; }
    #pragma unroll
    for (int dc = 0; dc < 8; ++dc){
      const int ch = dc*2 + hi;
      const bf16x8 k0 = *(const bf16x8*)(Ks + lq*256 + ((ch ^ (lq & 7)) * 16));
      const bf16x8 k1 = *(const bf16x8*)(Ks + (32 + lq)*256 + ((ch ^ (lq & 7)) * 16));
      s0 = __builtin_amdgcn_mfma_f32_32x32x16_bf16(k0, qf[dc], s0, 0, 0, 0);
      s1 = __builtin_amdgcn_mfma_f32_32x32x16_bf16(k1, qf[dc], s1, 0, 0, 0);
    }

    // online softmax; lane (lq,hi) holds P[k=crow(r,hi)(+32)][q=lq]
    float mt = s0[0];
    #pragma unroll
    for (int r = 1; r < 16; ++r) mt = fmaxf(mt, s0[r]);
    #pragma unroll
    for (int r = 0; r < 16; ++r) mt = fmaxf(mt, s1[r]);
    mt = fmaxf(mt, __shfl_xor(mt, 32));

    if (!__all(mt <= m + 8.0f)){
      const float mnew = fmaxf(m, mt);
      const float al = __expf(m - mnew);
      m = mnew;
      lsum *= al;
      float alb[16];
      #pragma unroll
      for (int r = 0; r < 16; ++r){
        const int crow = (r & 3) + 8*(r >> 2) + 4*hi;
        alb[r] = __shfl(al, crow);
      }
      #pragma unroll
      for (int nb = 0; nb < 4; ++nb)
        #pragma unroll
        for (int r = 0; r < 16; ++r) O[nb][r] *= alb[r];
    }

    float E[32];
    float sum = 0.0f;
    #pragma unroll
    for (int r = 0; r < 16; ++r){ E[r] = __expf(s0[r] - m); sum += E[r]; }
    #pragma unroll
    for (int r = 0; r < 16; ++r){ E[16 + r] = __expf(s1[r] - m); sum += E[16 + r]; }
    sum += __shfl_xor(sum, 32);
    lsum += sum;

    // repack P (column-local f32) -> PV A-fragments (row q, 8 consecutive k)
    bf16x8 pa[4];
    #pragma unroll
    for (int c = 0; c < 4; ++c){
      const int rb = c * 8;
      const uint a_ = pk2(E[rb + 0], E[rb + 1]);
      const uint b_ = pk2(E[rb + 2], E[rb + 3]);
      const uint c_ = pk2(E[rb + 4], E[rb + 5]);
      const uint d_ = pk2(E[rb + 6], E[rb + 7]);
      const uint sa = (uint)__shfl_xor((int)a_, 32);
      const uint sb = (uint)__shfl_xor((int)b_, 32);
      const uint sc = (uint)__shfl_xor((int)c_, 32);
      const uint sd = (uint)__shfl_xor((int)d_, 32);
      union { uint u[4]; bf16x8 v; } uu;
      uu.u[0] = hi ? sc : a_;
      uu.u[1] = hi ? sd : b_;
      uu.u[2] = hi ? c_ : sa;
      uu.u[3] = hi ? d_ : sb;
      pa[c] = uu.v;
    }

    // O += P * V  (A = P rows q, B = V^T rows d)
    #pragma unroll
    for (int c = 0; c < 4; ++c){
      const int ch = c*2 + hi;
      #pragma unroll
      for (int nb = 0; nb < 4; ++nb){
        const int vr = nb*32 + lq;
        const bf16x8 vf = *(const bf16x8*)(Vs + vr*128 + ((ch ^ (vr & 7)) * 16));
        O[nb] = __builtin_amdgcn_mfma_f32_32x32x16_bf16(pa[c], vf, O[nb], 0, 0, 0);
      }
    }
    __syncthreads();
  }

  const float rinv = 1.0f / lsum;
  float rb_[16];
  #pragma unroll
  for (int r = 0; r < 16; ++r){
    const int crow = (r & 3) + 8*(r >> 2) + 4*hi;
    rb_[r] = __shfl(rinv, crow);
  }
  #pragma unroll
  for (int nb = 0; nb < 4; ++nb)
    #pragma unroll
    for (int r = 0; r < 16; ++r){
      const int crow = (r & 3) + 8*(r >> 2) + 4*hi;
      o[(qbase + crow) * D_MODEL + cb + nb*32 + lq] = f2bf(O[nb][r] * rb_[r]);
    }
}

// ---------------------------------------------------------------------------
extern "C" void kernel_launch(void* const* d_in, const int* in_sizes, int n_in,
                              void* d_out, int out_size, void* d_ws, size_t ws_size,
                              hipStream_t stream){
  const float* hidden = (const float*)d_in[0];
  const float* Wq = (const float*)d_in[1];
  const float* Wc = (const float*)d_in[2];
  const float* Wk = (const float*)d_in[3];
  const float* Wv = (const float*)d_in[4];
  const float* Wo = (const float*)d_in[5];
  float* out = (float*)d_out;

  char* ws = (char*)d_ws;
  size_t off = 0;
  auto alloc = [&](size_t bytes)->char*{
    char* p = ws + off; off += (bytes + 255) & ~(size_t)255; return p;
  };
  unsigned short* Wqt  = (unsigned short*)alloc((size_t)D_MODEL * D_MODEL * 2);   // 32 MB
  unsigned short* Wct  = (unsigned short*)alloc((size_t)D_LATENT * D_MODEL * 2);
  unsigned short* Wkt  = (unsigned short*)alloc((size_t)D_MODEL * D_LATENT * 2);
  unsigned short* Wvt  = (unsigned short*)alloc((size_t)D_MODEL * D_LATENT * 2);
  unsigned short* Wot  = (unsigned short*)alloc((size_t)D_MODEL * D_MODEL * 2);   // 32 MB
  unsigned short* latent = (unsigned short*)alloc((size_t)ROWS * D_LATENT * 2);
  unsigned short* qbuf = (unsigned short*)alloc((size_t)ROWS * D_MODEL * 2);
  unsigned short* kbuf = (unsigned short*)alloc((size_t)ROWS * D_MODEL * 2);
  unsigned short* vbuf = (unsigned short*)alloc((size_t)ROWS * D_MODEL * 2);
  unsigned short* attnb= (unsigned short*)alloc((size_t)ROWS * D_MODEL * 2);
  float* ctab = (float*)alloc((size_t)SEQ * 64 * 4);
  float* stab = (float*)alloc((size_t)SEQ * 64 * 4);
  // V^T [64 bh][128][SEQ] aliases Wqt (dead after the Q projection GEMM)
  unsigned short* vtbuf = Wqt;

  const dim3 B256(256);
  const float qscale = 0.08838834764831845f;  // 1/sqrt(128)

  transpose_convert<<<dim3(64, 64), B256, 0, stream>>>(Wq, Wqt, D_MODEL, D_MODEL);
  transpose_convert<<<dim3(64, 8),  B256, 0, stream>>>(Wc, Wct, D_MODEL, D_LATENT);
  transpose_convert<<<dim3(8, 64),  B256, 0, stream>>>(Wk, Wkt, D_LATENT, D_MODEL);
  transpose_convert<<<dim3(8, 64),  B256, 0, stream>>>(Wv, Wvt, D_LATENT, D_MODEL);
  transpose_convert<<<dim3(64, 64), B256, 0, stream>>>(Wo, Wot, D_MODEL, D_MODEL);
  rope_table_kernel<<<512, B256, 0, stream>>>(ctab, stab);

  // projections
  gemm_kernel<true,  false><<<dim3(D_LATENT/128, ROWS/128), B256, 0, stream>>>(hidden, Wct, latent, ROWS, D_LATENT, D_MODEL);
  gemm_kernel<true,  false><<<dim3(D_MODEL/128,  ROWS/128), B256, 0, stream>>>(hidden, Wqt, qbuf,   ROWS, D_MODEL, D_MODEL);
  gemm_kernel<false, false><<<dim3(D_MODEL/128,  ROWS/128), B256, 0, stream>>>(latent, Wkt, kbuf,   ROWS, D_MODEL, D_LATENT);
  gemm_kernel<false, false><<<dim3(D_MODEL/128,  ROWS/128), B256, 0, stream>>>(latent, Wvt, vbuf,   ROWS, D_MODEL, D_LATENT);

  // V^T (overwrites Wqt region — Wqt is dead now)
  v_transpose<<<dim3(SEQ/64, HEAD_DIM/64, BATCH*NUM_HEADS), B256, 0, stream>>>(vbuf, vtbuf);

  // RoPE (scale folded into Q)
  rope_apply<<<(ROWS * NUM_HEADS * 64) / 256, B256, 0, stream>>>(qbuf, ctab, stab, qscale);
  rope_apply<<<(ROWS * NUM_HEADS * 64) / 256, B256, 0, stream>>>(kbuf, ctab, stab, 1.0f);

  // attention
  attn_kernel<<<dim3(SEQ/256, BATCH * NUM_HEADS), dim3(512), 0, stream>>>(qbuf, kbuf, vtbuf, attnb);

  // output projection (f32 out)
  gemm_kernel<false, true><<<dim3(D_MODEL/128, ROWS/128), B256, 0, stream>>>(attnb, Wot, out, ROWS, D_MODEL, D_MODEL);
}

// Round 3
// 795.846 us; speedup vs baseline: 1.7352x; 1.0869x over previous
//
#include <hip/hip_runtime.h>
#include <hip/hip_bf16.h>
#include <cstdint>
#include <cstddef>

#define D_MODEL 4096
#define D_LATENT 512
#define NUM_HEADS 32
#define HEAD_DIM 128
#define BATCH 2
#define SEQ 2048
#define ROWS (BATCH*SEQ)   // 4096

typedef __attribute__((ext_vector_type(8))) short bf16x8;
typedef __attribute__((ext_vector_type(4))) float f32x4;
typedef __attribute__((ext_vector_type(16))) float f32x16;
typedef unsigned int uint;

static __device__ __forceinline__ unsigned short f2bf(float f){
  union { float f; uint32_t u; } v; v.f = f;
  uint32_t r = (v.u + 0x7fffu + ((v.u >> 16) & 1u)) >> 16;
  return (unsigned short)r;
}
static __device__ __forceinline__ float bf2f(unsigned short h){
  union { uint32_t u; float f; } v; v.u = ((uint32_t)h) << 16;
  return v.f;
}
static __device__ __forceinline__ uint pk2(float lo, float hi2){
  return (uint)f2bf(lo) | ((uint)f2bf(hi2) << 16);
}
static __device__ __forceinline__ void gload16(const void* g, void* l){
  __builtin_amdgcn_global_load_lds(
      (const __attribute__((address_space(1))) void*)g,
      (__attribute__((address_space(3))) void*)l, 16, 0, 0);
}

// ---------------------------------------------------------------------------
// hidden f32 -> bf16, 8 elements/thread.
// ---------------------------------------------------------------------------
__global__ __launch_bounds__(256) void f32_to_bf16(
    const float* __restrict__ in, unsigned short* __restrict__ out){
  const size_t i = ((size_t)blockIdx.x * 256 + threadIdx.x) * 8;
  const float4 lo = *(const float4*)(in + i);
  const float4 hi = *(const float4*)(in + i + 4);
  uint4 d; unsigned short* dp = (unsigned short*)&d;
  dp[0]=f2bf(lo.x); dp[1]=f2bf(lo.y); dp[2]=f2bf(lo.z); dp[3]=f2bf(lo.w);
  dp[4]=f2bf(hi.x); dp[5]=f2bf(hi.y); dp[6]=f2bf(hi.z); dp[7]=f2bf(hi.w);
  *(uint4*)(out + i) = d;
}

// ---------------------------------------------------------------------------
// W [K][N] f32 (row-major) -> Wt [N][K] bf16 (row-major). 64x64 tiles.
// ---------------------------------------------------------------------------
__global__ __launch_bounds__(256) void transpose_convert(
    const float* __restrict__ W, unsigned short* __restrict__ Wt, int K, int N){
  __shared__ float tile[64][65];
  const int k0 = blockIdx.x * 64, n0 = blockIdx.y * 64;
  const int t = threadIdx.x;
  #pragma unroll
  for (int j = 0; j < 16; ++j){
    const int idx = t + 256*j;
    const int r = idx >> 6, c = idx & 63;
    tile[r][c] = W[(size_t)(k0 + r) * N + n0 + c];
  }
  __syncthreads();
  #pragma unroll
  for (int j = 0; j < 16; ++j){
    const int idx = t + 256*j;
    const int r = idx >> 6, c = idx & 63;   // r: n-local, c: k-local
    Wt[(size_t)(n0 + r) * K + k0 + c] = f2bf(tile[c][r]);
  }
}

// ---------------------------------------------------------------------------
// V [ROWS][D_MODEL] bf16 (row = b*SEQ+s, col = h*128+d) ->
// Vt [B*H][128][SEQ]  (vt[bh][d][s])
// ---------------------------------------------------------------------------
__global__ __launch_bounds__(256) void v_transpose(
    const unsigned short* __restrict__ v, unsigned short* __restrict__ vt){
  __shared__ unsigned short tile[64][72];
  const int s0 = blockIdx.x * 64, d0 = blockIdx.y * 64, bh = blockIdx.z;
  const int b = bh >> 5, h = bh & 31;
  const int t = threadIdx.x;
  #pragma unroll
  for (int j = 0; j < 2; ++j){
    const int idx = t + 256*j;
    const int r = idx >> 3, ch = idx & 7;
    *(uint4*)&tile[r][ch*8] =
      *(const uint4*)&v[(size_t)(b*SEQ + s0 + r) * D_MODEL + h*128 + d0 + ch*8];
  }
  __syncthreads();
  #pragma unroll
  for (int j = 0; j < 16; ++j){
    const int idx = t + 256*j;
    const int r = idx >> 6, c = idx & 63;
    vt[((size_t)bh*128 + d0 + r) * SEQ + s0 + c] = tile[c][r];
  }
}

// ---------------------------------------------------------------------------
// RoPE cos/sin tables: [SEQ][64] f32 each.
// ---------------------------------------------------------------------------
__global__ __launch_bounds__(256) void rope_table_kernel(float* __restrict__ ct,
                                                         float* __restrict__ st){
  const int i = blockIdx.x * 256 + threadIdx.x;
  if (i >= SEQ * 64) return;
  const int s = i >> 6, j = i & 63;
  const float inv = powf(10000.0f, -(float)j / 64.0f);
  const double a = (double)s * (double)inv;
  ct[i] = (float)cos(a);
  st[i] = (float)sin(a);
}

// ---------------------------------------------------------------------------
// In-place RoPE on bf16 buffer [ROWS][D_MODEL] viewed as [ROWS][H][128].
// ---------------------------------------------------------------------------
__global__ __launch_bounds__(256) void rope_apply(unsigned short* __restrict__ buf,
    const float* __restrict__ ct, const float* __restrict__ st, float scale){
  const int i = blockIdx.x * 256 + threadIdx.x;
  const int j = i & 63;
  const int tmp = i >> 6;
  const int h = tmp & 31;
  const int row = tmp >> 5;
  const int s = row & (SEQ - 1);
  const float c = ct[s*64 + j], sn = st[s*64 + j];
  const size_t base = (size_t)row * D_MODEL + (size_t)h * 128;
  const float x1 = bf2f(buf[base + j]);
  const float x2 = bf2f(buf[base + j + 64]);
  buf[base + j]      = f2bf((x1 * c - x2 * sn) * scale);
  buf[base + j + 64] = f2bf((x2 * c + x1 * sn) * scale);
}

// ---------------------------------------------------------------------------
// GEMM: C[M][N] = A[M][K] * Bt[N][K]^T.  A,Bt bf16. C: f32 or bf16.
// 128x128 tile, BK=64, 256 threads = 4 waves (2x2), 4x4 16x16x32 frags/wave.
// m97 structure: global_load_lds width=16 staging, linear LDS dest, XOR
// chunk-swizzle applied on the per-lane GLOBAL source address and on the
// ds_read side (both-sides rule). Single LDS buffer, 2 barriers per K-step.
// ---------------------------------------------------------------------------
template<bool OF32>
__global__ __launch_bounds__(256) void gemm_kernel(
    const unsigned short* __restrict__ A, const unsigned short* __restrict__ Bt,
    void* __restrict__ Cp, int M, int N, int K){
  __shared__ __align__(16) char As[128 * 128];
  __shared__ __align__(16) char Bs[128 * 128];
  const int t = threadIdx.x;
  const int m0 = blockIdx.y * 128, n0 = blockIdx.x * 128;
  const int l = t & 63, wid = t >> 6;
  const int wr = wid >> 1, wcn = wid & 1;
  const int lr = l & 15, lg = l >> 4;

  // staging: wave `wid` covers rows [wid*32, wid*32+32) of both tiles,
  // 4 issues x (64 lanes x 16B). lane l covers row wid*32+i*8+(l>>3),
  // physical chunk (l&7); its global chunk is XOR-swizzled:
  const int srow = l >> 3;               // 0..7
  const int gch  = (l & 7) ^ srow;       // global 16B-chunk index
  const unsigned short* gA = A  + (size_t)(m0 + wid*32 + srow) * K + gch*8;
  const unsigned short* gB = Bt + (size_t)(n0 + wid*32 + srow) * K + gch*8;
  char* lA = As + wid*4096;
  char* lB = Bs + wid*4096;

  f32x4 acc[4][4];
  #pragma unroll
  for (int i = 0; i < 4; ++i)
    #pragma unroll
    for (int j = 0; j < 4; ++j)
      #pragma unroll
      for (int r = 0; r < 4; ++r) acc[i][j][r] = 0.0f;

  const int kTiles = K >> 6;
  for (int kt = 0; kt < kTiles; ++kt){
    const size_t ko = (size_t)kt << 6;
    #pragma unroll
    for (int i = 0; i < 4; ++i){
      gload16(gA + (size_t)i*8*K + ko, lA + i*1024);
      gload16(gB + (size_t)i*8*K + ko, lB + i*1024);
    }
    __syncthreads();
    #pragma unroll
    for (int kc = 0; kc < 2; ++kc){
      bf16x8 af[4], bfv[4];
      const int ch = kc*4 + lg;
      #pragma unroll
      for (int mb = 0; mb < 4; ++mb){
        const int row = wr*64 + mb*16 + lr;
        af[mb] = *(const bf16x8*)(As + row*128 + ((ch ^ (row & 7)) * 16));
      }
      #pragma unroll
      for (int nb = 0; nb < 4; ++nb){
        const int row = wcn*64 + nb*16 + lr;
        bfv[nb] = *(const bf16x8*)(Bs + row*128 + ((ch ^ (row & 7)) * 16));
      }
      #pragma unroll
      for (int mb = 0; mb < 4; ++mb)
        #pragma unroll
        for (int nb = 0; nb < 4; ++nb)
          acc[mb][nb] = __builtin_amdgcn_mfma_f32_16x16x32_bf16(af[mb], bfv[nb], acc[mb][nb], 0, 0, 0);
    }
    __syncthreads();
  }
  #pragma unroll
  for (int mb = 0; mb < 4; ++mb)
    #pragma unroll
    for (int nb = 0; nb < 4; ++nb)
      #pragma unroll
      for (int r = 0; r < 4; ++r){
        const int row = m0 + wr*64 + mb*16 + lg*4 + r;
        const int col = n0 + wcn*64 + nb*16 + lr;
        if constexpr (OF32) ((float*)Cp)[(size_t)row * N + col] = acc[mb][nb][r];
        else ((unsigned short*)Cp)[(size_t)row * N + col] = f2bf(acc[mb][nb][r]);
      }
}

// ---------------------------------------------------------------------------
// Flash attention, 8 waves x 32 q-rows (QBLK=256), KVBLK=64, 32x32x16 MFMA.
// Swapped QK^T; in-register softmax + P repack; defer-max (THR=8).
// ---------------------------------------------------------------------------
__global__ __launch_bounds__(512) void attn_kernel(
    const unsigned short* __restrict__ q, const unsigned short* __restrict__ kp,
    const unsigned short* __restrict__ vt, unsigned short* __restrict__ o){
  __shared__ __align__(16) char Ks[64 * 256];
  __shared__ __align__(16) char Vs[128 * 128];
  const int t = threadIdx.x;
  const int l = t & 63, w = t >> 6;
  const int lq = l & 31, hi = l >> 5;
  const int qb = blockIdx.x, bh = blockIdx.y;
  const int b = bh >> 5;
  const size_t qbase = (size_t)b * SEQ + qb*256 + w*32;
  const size_t cb = (size_t)(bh & 31) * 128;

  bf16x8 qf[8];
  #pragma unroll
  for (int dc = 0; dc < 8; ++dc)
    qf[dc] = *(const bf16x8*)(q + (qbase + lq) * D_MODEL + cb + dc*16 + hi*8);

  f32x16 O[4];
  #pragma unroll
  for (int nb = 0; nb < 4; ++nb)
    #pragma unroll
    for (int r = 0; r < 16; ++r) O[nb][r] = 0.0f;
  float m = -1e30f, lsum = 0.0f;

  for (int kb = 0; kb < SEQ/64; ++kb){
    const size_t kr0 = (size_t)b * SEQ + kb*64;
    #pragma unroll
    for (int j = 0; j < 2; ++j){
      const int idx = t + 512*j;
      { const int r = idx >> 4, ch = idx & 15;
        *(uint4*)(Ks + r*256 + ((ch ^ (r & 7)) * 16)) =
          *(const uint4*)(kp + (kr0 + r) * D_MODEL + cb + ch*8); }
      { const int r = idx >> 3, ch = idx & 7;
        *(uint4*)(Vs + r*128 + ((ch ^ (r & 7)) * 16)) =
          *(const uint4*)(vt + ((size_t)bh*128 + r) * SEQ + kb*64 + ch*8); }
    }
    __syncthreads();

    f32x16 s0, s1;
    #pragma unroll
    for (int r = 0; r < 16; ++r){ s0[r] = 0.0f; s1[r] = 0.0f; }
    #pragma unroll
    for (int dc = 0; dc < 8; ++dc){
      const int ch = dc*2 + hi;
      const bf16x8 k0 = *(const bf16x8*)(Ks + lq*256 + ((ch ^ (lq & 7)) * 16));
      const bf16x8 k1 = *(const bf16x8*)(Ks + (32 + lq)*256 + ((ch ^ (lq & 7)) * 16));
      s0 = __builtin_amdgcn_mfma_f32_32x32x16_bf16(k0, qf[dc], s0, 0, 0, 0);
      s1 = __builtin_amdgcn_mfma_f32_32x32x16_bf16(k1, qf[dc], s1, 0, 0, 0);
    }

    float mt = s0[0];
    #pragma unroll
    for (int r = 1; r < 16; ++r) mt = fmaxf(mt, s0[r]);
    #pragma unroll
    for (int r = 0; r < 16; ++r) mt = fmaxf(mt, s1[r]);
    mt = fmaxf(mt, __shfl_xor(mt, 32));

    if (!__all(mt <= m + 8.0f)){
      const float mnew = fmaxf(m, mt);
      const float al = __expf(m - mnew);
      m = mnew;
      lsum *= al;
      float alb[16];
      #pragma unroll
      for (int r = 0; r < 16; ++r){
        const int crow = (r & 3) + 8*(r >> 2) + 4*hi;
        alb[r] = __shfl(al, crow);
      }
      #pragma unroll
      for (int nb = 0; nb < 4; ++nb)
        #pragma unroll
        for (int r = 0; r < 16; ++r) O[nb][r] *= alb[r];
    }

    float E[32];
    float sum = 0.0f;
    #pragma unroll
    for (int r = 0; r < 16; ++r){ E[r] = __expf(s0[r] - m); sum += E[r]; }
    #pragma unroll
    for (int r = 0; r < 16; ++r){ E[16 + r] = __expf(s1[r] - m); sum += E[16 + r]; }
    sum += __shfl_xor(sum, 32);
    lsum += sum;

    bf16x8 pa[4];
    #pragma unroll
    for (int c = 0; c < 4; ++c){
      const int rb = c * 8;
      const uint a_ = pk2(E[rb + 0], E[rb + 1]);
      const uint b_ = pk2(E[rb + 2], E[rb + 3]);
      const uint c_ = pk2(E[rb + 4], E[rb + 5]);
      const uint d_ = pk2(E[rb + 6], E[rb + 7]);
      const uint sa = (uint)__shfl_xor((int)a_, 32);
      const uint sb = (uint)__shfl_xor((int)b_, 32);
      const uint sc = (uint)__shfl_xor((int)c_, 32);
      const uint sd = (uint)__shfl_xor((int)d_, 32);
      union { uint u[4]; bf16x8 v; } uu;
      uu.u[0] = hi ? sc : a_;
      uu.u[1] = hi ? sd : b_;
      uu.u[2] = hi ? c_ : sa;
      uu.u[3] = hi ? d_ : sb;
      pa[c] = uu.v;
    }

    #pragma unroll
    for (int c = 0; c < 4; ++c){
      const int ch = c*2 + hi;
      #pragma unroll
      for (int nb = 0; nb < 4; ++nb){
        const int vr = nb*32 + lq;
        const bf16x8 vf = *(const bf16x8*)(Vs + vr*128 + ((ch ^ (vr & 7)) * 16));
        O[nb] = __builtin_amdgcn_mfma_f32_32x32x16_bf16(pa[c], vf, O[nb], 0, 0, 0);
      }
    }
    __syncthreads();
  }

  const float rinv = 1.0f / lsum;
  float rb_[16];
  #pragma unroll
  for (int r = 0; r < 16; ++r){
    const int crow = (r & 3) + 8*(r >> 2) + 4*hi;
    rb_[r] = __shfl(rinv, crow);
  }
  #pragma unroll
  for (int nb = 0; nb < 4; ++nb)
    #pragma unroll
    for (int r = 0; r < 16; ++r){
      const int crow = (r & 3) + 8*(r >> 2) + 4*hi;
      o[(qbase + crow) * D_MODEL + cb + nb*32 + lq] = f2bf(O[nb][r] * rb_[r]);
    }
}

// ---------------------------------------------------------------------------
extern "C" void kernel_launch(void* const* d_in, const int* in_sizes, int n_in,
                              void* d_out, int out_size, void* d_ws, size_t ws_size,
                              hipStream_t stream){
  const float* hidden = (const float*)d_in[0];
  const float* Wq = (const float*)d_in[1];
  const float* Wc = (const float*)d_in[2];
  const float* Wk = (const float*)d_in[3];
  const float* Wv = (const float*)d_in[4];
  const float* Wo = (const float*)d_in[5];
  float* out = (float*)d_out;

  char* ws = (char*)d_ws;
  size_t off = 0;
  auto alloc = [&](size_t bytes)->char*{
    char* p = ws + off; off += (bytes + 255) & ~(size_t)255; return p;
  };
  unsigned short* Wqt  = (unsigned short*)alloc((size_t)D_MODEL * D_MODEL * 2);
  unsigned short* Wct  = (unsigned short*)alloc((size_t)D_LATENT * D_MODEL * 2);
  unsigned short* Wkt  = (unsigned short*)alloc((size_t)D_MODEL * D_LATENT * 2);
  unsigned short* Wvt  = (unsigned short*)alloc((size_t)D_MODEL * D_LATENT * 2);
  unsigned short* Wot  = (unsigned short*)alloc((size_t)D_MODEL * D_MODEL * 2);
  unsigned short* latent = (unsigned short*)alloc((size_t)ROWS * D_LATENT * 2);
  unsigned short* qbuf = (unsigned short*)alloc((size_t)ROWS * D_MODEL * 2);
  unsigned short* kbuf = (unsigned short*)alloc((size_t)ROWS * D_MODEL * 2);
  unsigned short* vbuf = (unsigned short*)alloc((size_t)ROWS * D_MODEL * 2);
  unsigned short* attnb= (unsigned short*)alloc((size_t)ROWS * D_MODEL * 2);
  float* ctab = (float*)alloc((size_t)SEQ * 64 * 4);
  float* stab = (float*)alloc((size_t)SEQ * 64 * 4);
  // aliases: hidden_bf16 uses attnb's region (dead until attention writes it);
  // V^T uses Wqt's region (dead after the Q projection GEMM).
  unsigned short* hbf   = attnb;
  unsigned short* vtbuf = Wqt;

  const dim3 B256(256);
  const float qscale = 0.08838834764831845f;  // 1/sqrt(128)

  f32_to_bf16<<<(ROWS*(size_t)D_MODEL)/2048, B256, 0, stream>>>(hidden, hbf);
  transpose_convert<<<dim3(64, 64), B256, 0, stream>>>(Wq, Wqt, D_MODEL, D_MODEL);
  transpose_convert<<<dim3(64, 8),  B256, 0, stream>>>(Wc, Wct, D_MODEL, D_LATENT);
  transpose_convert<<<dim3(8, 64),  B256, 0, stream>>>(Wk, Wkt, D_LATENT, D_MODEL);
  transpose_convert<<<dim3(8, 64),  B256, 0, stream>>>(Wv, Wvt, D_LATENT, D_MODEL);
  transpose_convert<<<dim3(64, 64), B256, 0, stream>>>(Wo, Wot, D_MODEL, D_MODEL);
  rope_table_kernel<<<512, B256, 0, stream>>>(ctab, stab);

  // projections (all-bf16 A operands)
  gemm_kernel<false><<<dim3(D_LATENT/128, ROWS/128), B256, 0, stream>>>(hbf,    Wct, latent, ROWS, D_LATENT, D_MODEL);
  gemm_kernel<false><<<dim3(D_MODEL/128,  ROWS/128), B256, 0, stream>>>(hbf,    Wqt, qbuf,   ROWS, D_MODEL, D_MODEL);
  gemm_kernel<false><<<dim3(D_MODEL/128,  ROWS/128), B256, 0, stream>>>(latent, Wkt, kbuf,   ROWS, D_MODEL, D_LATENT);
  gemm_kernel<false><<<dim3(D_MODEL/128,  ROWS/128), B256, 0, stream>>>(latent, Wvt, vbuf,   ROWS, D_MODEL, D_LATENT);

  // V^T (overwrites Wqt region — dead now)
  v_transpose<<<dim3(SEQ/64, HEAD_DIM/64, BATCH*NUM_HEADS), B256, 0, stream>>>(vbuf, vtbuf);

  // RoPE (scale folded into Q)
  rope_apply<<<(ROWS * NUM_HEADS * 64) / 256, B256, 0, stream>>>(qbuf, ctab, stab, qscale);
  rope_apply<<<(ROWS * NUM_HEADS * 64) / 256, B256, 0, stream>>>(kbuf, ctab, stab, 1.0f);

  // attention (writes attnb == hbf, hbf is dead after Q-proj)
  attn_kernel<<<dim3(SEQ/256, BATCH * NUM_HEADS), dim3(512), 0, stream>>>(qbuf, kbuf, vtbuf, attnb);

  // output projection (f32 out)
  gemm_kernel<true><<<dim3(D_MODEL/128, ROWS/128), B256, 0, stream>>>(attnb, Wot, out, ROWS, D_MODEL, D_MODEL);
}

// Round 4
// 674.179 us; speedup vs baseline: 2.0483x; 1.1805x over previous
//
#include <hip/hip_runtime.h>
#include <hip/hip_bf16.h>
#include <cstdint>
#include <cstddef>

#define D_MODEL 4096
#define D_LATENT 512
#define NUM_HEADS 32
#define HEAD_DIM 128
#define BATCH 2
#define SEQ 2048
#define ROWS (BATCH*SEQ)   // 4096

typedef __attribute__((ext_vector_type(8))) short bf16x8;
typedef __attribute__((ext_vector_type(4))) float f32x4;
typedef __attribute__((ext_vector_type(16))) float f32x16;
typedef unsigned int uint;

static __device__ __forceinline__ unsigned short f2bf(float f){
  union { float f; uint32_t u; } v; v.f = f;
  uint32_t r = (v.u + 0x7fffu + ((v.u >> 16) & 1u)) >> 16;
  return (unsigned short)r;
}
static __device__ __forceinline__ float bf2f(unsigned short h){
  union { uint32_t u; float f; } v; v.u = ((uint32_t)h) << 16;
  return v.f;
}
static __device__ __forceinline__ uint pk2(float lo, float hi2){
  return (uint)f2bf(lo) | ((uint)f2bf(hi2) << 16);
}
static __device__ __forceinline__ void gload16(const void* g, void* l){
  __builtin_amdgcn_global_load_lds(
      (const __attribute__((address_space(1))) void*)g,
      (__attribute__((address_space(3))) void*)l, 16, 0, 0);
}

// ---------------------------------------------------------------------------
// hidden f32 -> bf16, 8 elements/thread.
// ---------------------------------------------------------------------------
__global__ __launch_bounds__(256) void f32_to_bf16(
    const float* __restrict__ in, unsigned short* __restrict__ out){
  const size_t i = ((size_t)blockIdx.x * 256 + threadIdx.x) * 8;
  const float4 lo = *(const float4*)(in + i);
  const float4 hi = *(const float4*)(in + i + 4);
  uint4 d; unsigned short* dp = (unsigned short*)&d;
  dp[0]=f2bf(lo.x); dp[1]=f2bf(lo.y); dp[2]=f2bf(lo.z); dp[3]=f2bf(lo.w);
  dp[4]=f2bf(hi.x); dp[5]=f2bf(hi.y); dp[6]=f2bf(hi.z); dp[7]=f2bf(hi.w);
  *(uint4*)(out + i) = d;
}

// ---------------------------------------------------------------------------
// W [K][N] f32 (row-major) -> Wt [N][K] bf16 (row-major). 64x64 tiles.
// ---------------------------------------------------------------------------
__global__ __launch_bounds__(256) void transpose_convert(
    const float* __restrict__ W, unsigned short* __restrict__ Wt, int K, int N){
  __shared__ float tile[64][65];
  const int k0 = blockIdx.x * 64, n0 = blockIdx.y * 64;
  const int t = threadIdx.x;
  #pragma unroll
  for (int j = 0; j < 16; ++j){
    const int idx = t + 256*j;
    const int r = idx >> 6, c = idx & 63;
    tile[r][c] = W[(size_t)(k0 + r) * N + n0 + c];
  }
  __syncthreads();
  #pragma unroll
  for (int j = 0; j < 16; ++j){
    const int idx = t + 256*j;
    const int r = idx >> 6, c = idx & 63;
    Wt[(size_t)(n0 + r) * K + k0 + c] = f2bf(tile[c][r]);
  }
}

// ---------------------------------------------------------------------------
// V [ROWS][D_MODEL] bf16 -> Vt [B*H][128][SEQ]
// ---------------------------------------------------------------------------
__global__ __launch_bounds__(256) void v_transpose(
    const unsigned short* __restrict__ v, unsigned short* __restrict__ vt){
  __shared__ unsigned short tile[64][72];
  const int s0 = blockIdx.x * 64, d0 = blockIdx.y * 64, bh = blockIdx.z;
  const int b = bh >> 5, h = bh & 31;
  const int t = threadIdx.x;
  #pragma unroll
  for (int j = 0; j < 2; ++j){
    const int idx = t + 256*j;
    const int r = idx >> 3, ch = idx & 7;
    *(uint4*)&tile[r][ch*8] =
      *(const uint4*)&v[(size_t)(b*SEQ + s0 + r) * D_MODEL + h*128 + d0 + ch*8];
  }
  __syncthreads();
  #pragma unroll
  for (int j = 0; j < 16; ++j){
    const int idx = t + 256*j;
    const int r = idx >> 6, c = idx & 63;
    vt[((size_t)bh*128 + d0 + r) * SEQ + s0 + c] = tile[c][r];
  }
}

// ---------------------------------------------------------------------------
// RoPE cos/sin tables: [SEQ][64] f32 each.
// ---------------------------------------------------------------------------
__global__ __launch_bounds__(256) void rope_table_kernel(float* __restrict__ ct,
                                                         float* __restrict__ st){
  const int i = blockIdx.x * 256 + threadIdx.x;
  if (i >= SEQ * 64) return;
  const int s = i >> 6, j = i & 63;
  const float inv = powf(10000.0f, -(float)j / 64.0f);
  const double a = (double)s * (double)inv;
  ct[i] = (float)cos(a);
  st[i] = (float)sin(a);
}

// ---------------------------------------------------------------------------
// In-place RoPE on bf16 buffer [ROWS][D_MODEL] viewed as [ROWS][H][128].
// ---------------------------------------------------------------------------
__global__ __launch_bounds__(256) void rope_apply(unsigned short* __restrict__ buf,
    const float* __restrict__ ct, const float* __restrict__ st, float scale){
  const int i = blockIdx.x * 256 + threadIdx.x;
  const int j = i & 63;
  const int tmp = i >> 6;
  const int h = tmp & 31;
  const int row = tmp >> 5;
  const int s = row & (SEQ - 1);
  const float c = ct[s*64 + j], sn = st[s*64 + j];
  const size_t base = (size_t)row * D_MODEL + (size_t)h * 128;
  const float x1 = bf2f(buf[base + j]);
  const float x2 = bf2f(buf[base + j + 64]);
  buf[base + j]      = f2bf((x1 * c - x2 * sn) * scale);
  buf[base + j + 64] = f2bf((x2 * c + x1 * sn) * scale);
}

// ---------------------------------------------------------------------------
// 128x128 m97-structure GEMM (kept for small-N latent projection).
// ---------------------------------------------------------------------------
template<bool OF32>
__global__ __launch_bounds__(256) void gemm_kernel(
    const unsigned short* __restrict__ A, const unsigned short* __restrict__ Bt,
    void* __restrict__ Cp, int M, int N, int K){
  __shared__ __align__(16) char As[128 * 128];
  __shared__ __align__(16) char Bs[128 * 128];
  const int t = threadIdx.x;
  const int m0 = blockIdx.y * 128, n0 = blockIdx.x * 128;
  const int l = t & 63, wid = t >> 6;
  const int wr = wid >> 1, wcn = wid & 1;
  const int lr = l & 15, lg = l >> 4;

  const int srow = l >> 3;
  const int gch  = (l & 7) ^ srow;
  const unsigned short* gA = A  + (size_t)(m0 + wid*32 + srow) * K + gch*8;
  const unsigned short* gB = Bt + (size_t)(n0 + wid*32 + srow) * K + gch*8;
  char* lA = As + wid*4096;
  char* lB = Bs + wid*4096;

  f32x4 acc[4][4];
  #pragma unroll
  for (int i = 0; i < 4; ++i)
    #pragma unroll
    for (int j = 0; j < 4; ++j)
      #pragma unroll
      for (int r = 0; r < 4; ++r) acc[i][j][r] = 0.0f;

  const int kTiles = K >> 6;
  for (int kt = 0; kt < kTiles; ++kt){
    const size_t ko = (size_t)kt << 6;
    #pragma unroll
    for (int i = 0; i < 4; ++i){
      gload16(gA + (size_t)i*8*K + ko, lA + i*1024);
      gload16(gB + (size_t)i*8*K + ko, lB + i*1024);
    }
    __syncthreads();
    #pragma unroll
    for (int kc = 0; kc < 2; ++kc){
      bf16x8 af[4], bfv[4];
      const int ch = kc*4 + lg;
      #pragma unroll
      for (int mb = 0; mb < 4; ++mb){
        const int row = wr*64 + mb*16 + lr;
        af[mb] = *(const bf16x8*)(As + row*128 + ((ch ^ (row & 7)) * 16));
      }
      #pragma unroll
      for (int nb = 0; nb < 4; ++nb){
        const int row = wcn*64 + nb*16 + lr;
        bfv[nb] = *(const bf16x8*)(Bs + row*128 + ((ch ^ (row & 7)) * 16));
      }
      #pragma unroll
      for (int mb = 0; mb < 4; ++mb)
        #pragma unroll
        for (int nb = 0; nb < 4; ++nb)
          acc[mb][nb] = __builtin_amdgcn_mfma_f32_16x16x32_bf16(af[mb], bfv[nb], acc[mb][nb], 0, 0, 0);
    }
    __syncthreads();
  }
  #pragma unroll
  for (int mb = 0; mb < 4; ++mb)
    #pragma unroll
    for (int nb = 0; nb < 4; ++nb)
      #pragma unroll
      for (int r = 0; r < 4; ++r){
        const int row = m0 + wr*64 + mb*16 + lg*4 + r;
        const int col = n0 + wcn*64 + nb*16 + lr;
        if constexpr (OF32) ((float*)Cp)[(size_t)row * N + col] = acc[mb][nb][r];
        else ((unsigned short*)Cp)[(size_t)row * N + col] = f2bf(acc[mb][nb][r]);
      }
}

// ---------------------------------------------------------------------------
// 256x256 8-phase GEMM (T2+T3+T4+T5). BK=64, 512 thr = 8 waves (2M x 4N),
// per-wave C 128x64 (8m x 4n 16x16 frags). 128 KiB LDS: 2 K-tile dbuf.
// Per phase: {ds_read quadrant frags | stage 1 half-tile (2 gload_lds)} ->
// barrier -> lgkmcnt(0) -> setprio(1)+16 MFMA -> barrier. Counted vmcnt(2)
// fences at phases 4 & 8 only (never drain in main loop).
// ---------------------------------------------------------------------------
template<int MH>
static __device__ __forceinline__ void rdAh(bf16x8 (&a_)[4][2], const char* buf,
                                            int wr, int lr, int lg){
  #pragma unroll
  for (int mm = 0; mm < 4; ++mm)
    #pragma unroll
    for (int kc = 0; kc < 2; ++kc){
      const int row = wr*128 + (MH*4 + mm)*16 + lr;
      const int ch = kc*4 + lg;
      a_[mm][kc] = *(const bf16x8*)(buf + row*128 + ((ch ^ (row & 7)) * 16));
    }
}
template<int NH>
static __device__ __forceinline__ void rdBh(bf16x8 (&b_)[2][2][2], const char* buf,
                                            int wc, int lr, int lg){
  #pragma unroll
  for (int nn = 0; nn < 2; ++nn)
    #pragma unroll
    for (int kc = 0; kc < 2; ++kc){
      const int row = wc*64 + (NH*2 + nn)*16 + lr;
      const int ch = kc*4 + lg;
      b_[NH][nn][kc] = *(const bf16x8*)(buf + row*128 + ((ch ^ (row & 7)) * 16));
    }
}
template<int MH, int NH>
static __device__ __forceinline__ void mfq(f32x4 (&acc)[8][4],
    const bf16x8 (&a_)[4][2], const bf16x8 (&b_)[2][2][2]){
  __builtin_amdgcn_s_setprio(1);
  #pragma unroll
  for (int kc = 0; kc < 2; ++kc)
    #pragma unroll
    for (int mm = 0; mm < 4; ++mm)
      #pragma unroll
      for (int nn = 0; nn < 2; ++nn)
        acc[MH*4+mm][NH*2+nn] = __builtin_amdgcn_mfma_f32_16x16x32_bf16(
            a_[mm][kc], b_[NH][nn][kc], acc[MH*4+mm][NH*2+nn], 0, 0, 0);
  __builtin_amdgcn_s_setprio(0);
}

#define G256_BAR  __builtin_amdgcn_s_barrier()
#define G256_LGK0 do{ asm volatile("s_waitcnt lgkmcnt(0)" ::: "memory"); \
                      __builtin_amdgcn_sched_barrier(0); }while(0)
#define G256_VM(n) asm volatile("s_waitcnt vmcnt(" #n ")" ::: "memory")

template<bool OF32>
__global__ __launch_bounds__(512, 2) void gemm256_kernel(
    const unsigned short* __restrict__ A, const unsigned short* __restrict__ Bt,
    void* __restrict__ Cp, int M, int N, int K){
  __shared__ __align__(16) char lds[131072];
  char* const As0 = lds;
  char* const As1 = lds + 32768;
  char* const Bs0 = lds + 65536;
  char* const Bs1 = lds + 98304;

  const int t = threadIdx.x;
  const int l = t & 63, wid = t >> 6;
  const int wr = wid >> 2, wc = wid & 3;
  const int lr = l & 15, lg = l >> 4;
  const int m0 = blockIdx.y * 256, n0 = blockIdx.x * 256;

  // staging: thread t covers row (t>>3) within a 64-row issue block,
  // physical 16B chunk (t&7), global chunk XOR-swizzled.
  const int srow = t >> 3;
  const int pch = t & 7;
  const int gch = pch ^ (srow & 7);
  const unsigned short* gAb = A  + (size_t)(m0 + srow) * K + gch*8;
  const unsigned short* gBb = Bt + (size_t)(n0 + srow) * K + gch*8;
  const int ldso = srow*128 + pch*16;

  auto stA = [&](char* dst, int half, int kcol){
    const unsigned short* g = gAb + (size_t)half*128*K + kcol;
    gload16(g,                dst + half*16384 + ldso);
    gload16(g + (size_t)64*K, dst + half*16384 + 8192 + ldso);
  };
  auto stB = [&](char* dst, int half, int kcol){
    const unsigned short* g = gBb + (size_t)half*128*K + kcol;
    gload16(g,                dst + half*16384 + ldso);
    gload16(g + (size_t)64*K, dst + half*16384 + 8192 + ldso);
  };

  f32x4 acc[8][4];
  #pragma unroll
  for (int m = 0; m < 8; ++m)
    #pragma unroll
    for (int n = 0; n < 4; ++n)
      #pragma unroll
      for (int r = 0; r < 4; ++r) acc[m][n][r] = 0.0f;
  bf16x8 a_[4][2];
  bf16x8 b_[2][2][2];

  const int niter = K >> 7;
  // prologue: buf0 = K-tile 0 (4 half-tiles), buf1 HT1 (A of K-tile 1)
  stA(As0, 0, 0); stA(As0, 1, 0); stB(Bs0, 0, 0); stB(Bs0, 1, 0);
  stA(As1, 0, 64);
  G256_VM(2);
  G256_BAR;
  __builtin_amdgcn_sched_barrier(0);

  for (int j = 0; j < niter; ++j){
    const int k0 = j << 7;
    const bool more = (j + 1 < niter);
    // P1: reads buf0 A-mh0 + B-nh0; stage buf1 HT2 (A half1 of kt1)
    rdAh<0>(a_, As0, wr, lr, lg);
    rdBh<0>(b_, Bs0, wc, lr, lg);
    stA(As1, 1, k0 + 64);
    G256_BAR; G256_LGK0;
    mfq<0,0>(acc, a_, b_);
    G256_BAR;
    // P2: B-nh1; stage buf1 HT3 (B half0)
    rdBh<1>(b_, Bs0, wc, lr, lg);
    stB(Bs1, 0, k0 + 64);
    G256_BAR; G256_LGK0;
    mfq<0,1>(acc, a_, b_);
    G256_BAR;
    // P3: A-mh1; stage buf1 HT4 (B half1)
    rdAh<1>(a_, As0, wr, lr, lg);
    stB(Bs1, 1, k0 + 64);
    G256_BAR; G256_LGK0;
    mfq<1,0>(acc, a_, b_);
    G256_BAR;
    // P4: stage buf0' HT1 (A half0 of kt0+2); fence confirms buf1 complete
    if (more){ stA(As0, 0, k0 + 128); G256_VM(2); }
    else     { G256_VM(0); }
    G256_BAR;
    __builtin_amdgcn_sched_barrier(0);
    mfq<1,1>(acc, a_, b_);
    G256_BAR;
    // P5: reads buf1; stage buf0' HT2
    rdAh<0>(a_, As1, wr, lr, lg);
    rdBh<0>(b_, Bs1, wc, lr, lg);
    if (more) stA(As0, 1, k0 + 128);
    G256_BAR; G256_LGK0;
    mfq<0,0>(acc, a_, b_);
    G256_BAR;
    // P6: stage buf0' HT3
    rdBh<1>(b_, Bs1, wc, lr, lg);
    if (more) stB(Bs0, 0, k0 + 128);
    G256_BAR; G256_LGK0;
    mfq<0,1>(acc, a_, b_);
    G256_BAR;
    // P7: stage buf0' HT4
    rdAh<1>(a_, As1, wr, lr, lg);
    if (more) stB(Bs0, 1, k0 + 128);
    G256_BAR; G256_LGK0;
    mfq<1,0>(acc, a_, b_);
    G256_BAR;
    // P8: stage buf1' HT1 (A half0 of kt1+2); fence confirms buf0' complete
    if (more){ stA(As1, 0, k0 + 192); G256_VM(2); }
    G256_BAR;
    __builtin_amdgcn_sched_barrier(0);
    mfq<1,1>(acc, a_, b_);
    G256_BAR;
  }

  #pragma unroll
  for (int m = 0; m < 8; ++m)
    #pragma unroll
    for (int n = 0; n < 4; ++n)
      #pragma unroll
      for (int r = 0; r < 4; ++r){
        const int row = m0 + wr*128 + m*16 + lg*4 + r;
        const int col = n0 + wc*64 + n*16 + lr;
        if constexpr (OF32) ((float*)Cp)[(size_t)row * N + col] = acc[m][n][r];
        else ((unsigned short*)Cp)[(size_t)row * N + col] = f2bf(acc[m][n][r]);
      }
}

// ---------------------------------------------------------------------------
// Flash attention, 8 waves x 32 q-rows (QBLK=256), KVBLK=64, 32x32x16 MFMA.
// ---------------------------------------------------------------------------
__global__ __launch_bounds__(512) void attn_kernel(
    const unsigned short* __restrict__ q, const unsigned short* __restrict__ kp,
    const unsigned short* __restrict__ vt, unsigned short* __restrict__ o){
  __shared__ __align__(16) char Ks[64 * 256];
  __shared__ __align__(16) char Vs[128 * 128];
  const int t = threadIdx.x;
  const int l = t & 63, w = t >> 6;
  const int lq = l & 31, hi = l >> 5;
  const int qb = blockIdx.x, bh = blockIdx.y;
  const int b = bh >> 5;
  const size_t qbase = (size_t)b * SEQ + qb*256 + w*32;
  const size_t cb = (size_t)(bh & 31) * 128;

  bf16x8 qf[8];
  #pragma unroll
  for (int dc = 0; dc < 8; ++dc)
    qf[dc] = *(const bf16x8*)(q + (qbase + lq) * D_MODEL + cb + dc*16 + hi*8);

  f32x16 O[4];
  #pragma unroll
  for (int nb = 0; nb < 4; ++nb)
    #pragma unroll
    for (int r = 0; r < 16; ++r) O[nb][r] = 0.0f;
  float m = -1e30f, lsum = 0.0f;

  for (int kb = 0; kb < SEQ/64; ++kb){
    const size_t kr0 = (size_t)b * SEQ + kb*64;
    #pragma unroll
    for (int j = 0; j < 2; ++j){
      const int idx = t + 512*j;
      { const int r = idx >> 4, ch = idx & 15;
        *(uint4*)(Ks + r*256 + ((ch ^ (r & 7)) * 16)) =
          *(const uint4*)(kp + (kr0 + r) * D_MODEL + cb + ch*8); }
      { const int r = idx >> 3, ch = idx & 7;
        *(uint4*)(Vs + r*128 + ((ch ^ (r & 7)) * 16)) =
          *(const uint4*)(vt + ((size_t)bh*128 + r) * SEQ + kb*64 + ch*8); }
    }
    __syncthreads();

    f32x16 s0, s1;
    #pragma unroll
    for (int r = 0; r < 16; ++r){ s0[r] = 0.0f; s1[r] = 0.0f; }
    #pragma unroll
    for (int dc = 0; dc < 8; ++dc){
      const int ch = dc*2 + hi;
      const bf16x8 k0 = *(const bf16x8*)(Ks + lq*256 + ((ch ^ (lq & 7)) * 16));
      const bf16x8 k1 = *(const bf16x8*)(Ks + (32 + lq)*256 + ((ch ^ (lq & 7)) * 16));
      s0 = __builtin_amdgcn_mfma_f32_32x32x16_bf16(k0, qf[dc], s0, 0, 0, 0);
      s1 = __builtin_amdgcn_mfma_f32_32x32x16_bf16(k1, qf[dc], s1, 0, 0, 0);
    }

    float mt = s0[0];
    #pragma unroll
    for (int r = 1; r < 16; ++r) mt = fmaxf(mt, s0[r]);
    #pragma unroll
    for (int r = 0; r < 16; ++r) mt = fmaxf(mt, s1[r]);
    mt = fmaxf(mt, __shfl_xor(mt, 32));

    if (!__all(mt <= m + 8.0f)){
      const float mnew = fmaxf(m, mt);
      const float al = __expf(m - mnew);
      m = mnew;
      lsum *= al;
      float alb[16];
      #pragma unroll
      for (int r = 0; r < 16; ++r){
        const int crow = (r & 3) + 8*(r >> 2) + 4*hi;
        alb[r] = __shfl(al, crow);
      }
      #pragma unroll
      for (int nb = 0; nb < 4; ++nb)
        #pragma unroll
        for (int r = 0; r < 16; ++r) O[nb][r] *= alb[r];
    }

    float E[32];
    float sum = 0.0f;
    #pragma unroll
    for (int r = 0; r < 16; ++r){ E[r] = __expf(s0[r] - m); sum += E[r]; }
    #pragma unroll
    for (int r = 0; r < 16; ++r){ E[16 + r] = __expf(s1[r] - m); sum += E[16 + r]; }
    sum += __shfl_xor(sum, 32);
    lsum += sum;

    bf16x8 pa[4];
    #pragma unroll
    for (int c = 0; c < 4; ++c){
      const int rb = c * 8;
      const uint a_ = pk2(E[rb + 0], E[rb + 1]);
      const uint b_ = pk2(E[rb + 2], E[rb + 3]);
      const uint c_ = pk2(E[rb + 4], E[rb + 5]);
      const uint d_ = pk2(E[rb + 6], E[rb + 7]);
      const uint sa = (uint)__shfl_xor((int)a_, 32);
      const uint sb = (uint)__shfl_xor((int)b_, 32);
      const uint sc = (uint)__shfl_xor((int)c_, 32);
      const uint sd = (uint)__shfl_xor((int)d_, 32);
      union { uint u[4]; bf16x8 v; } uu;
      uu.u[0] = hi ? sc : a_;
      uu.u[1] = hi ? sd : b_;
      uu.u[2] = hi ? c_ : sa;
      uu.u[3] = hi ? d_ : sb;
      pa[c] = uu.v;
    }

    #pragma unroll
    for (int c = 0; c < 4; ++c){
      const int ch = c*2 + hi;
      #pragma unroll
      for (int nb = 0; nb < 4; ++nb){
        const int vr = nb*32 + lq;
        const bf16x8 vf = *(const bf16x8*)(Vs + vr*128 + ((ch ^ (vr & 7)) * 16));
        O[nb] = __builtin_amdgcn_mfma_f32_32x32x16_bf16(pa[c], vf, O[nb], 0, 0, 0);
      }
    }
    __syncthreads();
  }

  const float rinv = 1.0f / lsum;
  float rb_[16];
  #pragma unroll
  for (int r = 0; r < 16; ++r){
    const int crow = (r & 3) + 8*(r >> 2) + 4*hi;
    rb_[r] = __shfl(rinv, crow);
  }
  #pragma unroll
  for (int nb = 0; nb < 4; ++nb)
    #pragma unroll
    for (int r = 0; r < 16; ++r){
      const int crow = (r & 3) + 8*(r >> 2) + 4*hi;
      o[(qbase + crow) * D_MODEL + cb + nb*32 + lq] = f2bf(O[nb][r] * rb_[r]);
    }
}

// ---------------------------------------------------------------------------
extern "C" void kernel_launch(void* const* d_in, const int* in_sizes, int n_in,
                              void* d_out, int out_size, void* d_ws, size_t ws_size,
                              hipStream_t stream){
  const float* hidden = (const float*)d_in[0];
  const float* Wq = (const float*)d_in[1];
  const float* Wc = (const float*)d_in[2];
  const float* Wk = (const float*)d_in[3];
  const float* Wv = (const float*)d_in[4];
  const float* Wo = (const float*)d_in[5];
  float* out = (float*)d_out;

  char* ws = (char*)d_ws;
  size_t off = 0;
  auto alloc = [&](size_t bytes)->char*{
    char* p = ws + off; off += (bytes + 255) & ~(size_t)255; return p;
  };
  unsigned short* Wqt  = (unsigned short*)alloc((size_t)D_MODEL * D_MODEL * 2);
  unsigned short* Wct  = (unsigned short*)alloc((size_t)D_LATENT * D_MODEL * 2);
  unsigned short* Wkt  = (unsigned short*)alloc((size_t)D_MODEL * D_LATENT * 2);
  unsigned short* Wvt  = (unsigned short*)alloc((size_t)D_MODEL * D_LATENT * 2);
  unsigned short* Wot  = (unsigned short*)alloc((size_t)D_MODEL * D_MODEL * 2);
  unsigned short* latent = (unsigned short*)alloc((size_t)ROWS * D_LATENT * 2);
  unsigned short* qbuf = (unsigned short*)alloc((size_t)ROWS * D_MODEL * 2);
  unsigned short* kbuf = (unsigned short*)alloc((size_t)ROWS * D_MODEL * 2);
  unsigned short* vbuf = (unsigned short*)alloc((size_t)ROWS * D_MODEL * 2);
  unsigned short* attnb= (unsigned short*)alloc((size_t)ROWS * D_MODEL * 2);
  float* ctab = (float*)alloc((size_t)SEQ * 64 * 4);
  float* stab = (float*)alloc((size_t)SEQ * 64 * 4);
  unsigned short* hbf   = attnb;  // alias: dead until attention writes it
  unsigned short* vtbuf = Wqt;    // alias: dead after Q-proj

  const dim3 B256(256);
  const float qscale = 0.08838834764831845f;  // 1/sqrt(128)

  f32_to_bf16<<<(ROWS*(size_t)D_MODEL)/2048, B256, 0, stream>>>(hidden, hbf);
  transpose_convert<<<dim3(64, 64), B256, 0, stream>>>(Wq, Wqt, D_MODEL, D_MODEL);
  transpose_convert<<<dim3(64, 8),  B256, 0, stream>>>(Wc, Wct, D_MODEL, D_LATENT);
  transpose_convert<<<dim3(8, 64),  B256, 0, stream>>>(Wk, Wkt, D_LATENT, D_MODEL);
  transpose_convert<<<dim3(8, 64),  B256, 0, stream>>>(Wv, Wvt, D_LATENT, D_MODEL);
  transpose_convert<<<dim3(64, 64), B256, 0, stream>>>(Wo, Wot, D_MODEL, D_MODEL);
  rope_table_kernel<<<512, B256, 0, stream>>>(ctab, stab);

  // projections
  gemm_kernel<false><<<dim3(D_LATENT/128, ROWS/128), B256, 0, stream>>>(hbf, Wct, latent, ROWS, D_LATENT, D_MODEL);
  gemm256_kernel<false><<<dim3(D_MODEL/256, ROWS/256), dim3(512), 0, stream>>>(hbf,    Wqt, qbuf, ROWS, D_MODEL, D_MODEL);
  gemm256_kernel<false><<<dim3(D_MODEL/256, ROWS/256), dim3(512), 0, stream>>>(latent, Wkt, kbuf, ROWS, D_MODEL, D_LATENT);
  gemm256_kernel<false><<<dim3(D_MODEL/256, ROWS/256), dim3(512), 0, stream>>>(latent, Wvt, vbuf, ROWS, D_MODEL, D_LATENT);

  // V^T (overwrites Wqt region — dead now)
  v_transpose<<<dim3(SEQ/64, HEAD_DIM/64, BATCH*NUM_HEADS), B256, 0, stream>>>(vbuf, vtbuf);

  // RoPE (scale folded into Q)
  rope_apply<<<(ROWS * NUM_HEADS * 64) / 256, B256, 0, stream>>>(qbuf, ctab, stab, qscale);
  rope_apply<<<(ROWS * NUM_HEADS * 64) / 256, B256, 0, stream>>>(kbuf, ctab, stab, 1.0f);

  // attention (writes attnb == hbf, hbf dead after projections)
  attn_kernel<<<dim3(SEQ/256, BATCH * NUM_HEADS), dim3(512), 0, stream>>>(qbuf, kbuf, vtbuf, attnb);

  // output projection (f32 out)
  gemm256_kernel<true><<<dim3(D_MODEL/256, ROWS/256), dim3(512), 0, stream>>>(attnb, Wot, out, ROWS, D_MODEL, D_MODEL);
}

// Round 5
// 653.176 us; speedup vs baseline: 2.1142x; 1.0322x over previous
//
#include <hip/hip_runtime.h>
#include <hip/hip_bf16.h>
#include <cstdint>
#include <cstddef>

#define D_MODEL 4096
#define D_LATENT 512
#define NUM_HEADS 32
#define HEAD_DIM 128
#define BATCH 2
#define SEQ 2048
#define ROWS (BATCH*SEQ)   // 4096

typedef __attribute__((ext_vector_type(8))) short bf16x8;
typedef __attribute__((ext_vector_type(4))) float f32x4;
typedef __attribute__((ext_vector_type(16))) float f32x16;
typedef unsigned int uint;

static __device__ __forceinline__ unsigned short f2bf(float f){
  union { float f; uint32_t u; } v; v.f = f;
  uint32_t r = (v.u + 0x7fffu + ((v.u >> 16) & 1u)) >> 16;
  return (unsigned short)r;
}
static __device__ __forceinline__ float bf2f(unsigned short h){
  union { uint32_t u; float f; } v; v.u = ((uint32_t)h) << 16;
  return v.f;
}
static __device__ __forceinline__ uint cvtpk(float lo, float hi2){
  uint r;
  asm("v_cvt_pk_bf16_f32 %0, %1, %2" : "=v"(r) : "v"(lo), "v"(hi2));
  return r;
}
static __device__ __forceinline__ void gload16(const void* g, void* l){
  __builtin_amdgcn_global_load_lds(
      (const __attribute__((address_space(1))) void*)g,
      (__attribute__((address_space(3))) void*)l, 16, 0, 0);
}

// ---------------------------------------------------------------------------
// hidden f32 -> bf16, 8 elements/thread.
// ---------------------------------------------------------------------------
__global__ __launch_bounds__(256) void f32_to_bf16(
    const float* __restrict__ in, unsigned short* __restrict__ out){
  const size_t i = ((size_t)blockIdx.x * 256 + threadIdx.x) * 8;
  const float4 lo = *(const float4*)(in + i);
  const float4 hi = *(const float4*)(in + i + 4);
  uint4 d; unsigned short* dp = (unsigned short*)&d;
  dp[0]=f2bf(lo.x); dp[1]=f2bf(lo.y); dp[2]=f2bf(lo.z); dp[3]=f2bf(lo.w);
  dp[4]=f2bf(hi.x); dp[5]=f2bf(hi.y); dp[6]=f2bf(hi.z); dp[7]=f2bf(hi.w);
  *(uint4*)(out + i) = d;
}

// ---------------------------------------------------------------------------
// W [K][N] f32 (row-major) -> Wt [N][K] bf16 (row-major). 64x64 tiles.
// ---------------------------------------------------------------------------
__global__ __launch_bounds__(256) void transpose_convert(
    const float* __restrict__ W, unsigned short* __restrict__ Wt, int K, int N){
  __shared__ float tile[64][65];
  const int k0 = blockIdx.x * 64, n0 = blockIdx.y * 64;
  const int t = threadIdx.x;
  #pragma unroll
  for (int j = 0; j < 16; ++j){
    const int idx = t + 256*j;
    const int r = idx >> 6, c = idx & 63;
    tile[r][c] = W[(size_t)(k0 + r) * N + n0 + c];
  }
  __syncthreads();
  #pragma unroll
  for (int j = 0; j < 16; ++j){
    const int idx = t + 256*j;
    const int r = idx >> 6, c = idx & 63;
    Wt[(size_t)(n0 + r) * K + k0 + c] = f2bf(tile[c][r]);
  }
}

// ---------------------------------------------------------------------------
// V [ROWS][D_MODEL] bf16 -> Vt [B*H][128][SEQ]
// ---------------------------------------------------------------------------
__global__ __launch_bounds__(256) void v_transpose(
    const unsigned short* __restrict__ v, unsigned short* __restrict__ vt){
  __shared__ unsigned short tile[64][72];
  const int s0 = blockIdx.x * 64, d0 = blockIdx.y * 64, bh = blockIdx.z;
  const int b = bh >> 5, h = bh & 31;
  const int t = threadIdx.x;
  #pragma unroll
  for (int j = 0; j < 2; ++j){
    const int idx = t + 256*j;
    const int r = idx >> 3, ch = idx & 7;
    *(uint4*)&tile[r][ch*8] =
      *(const uint4*)&v[(size_t)(b*SEQ + s0 + r) * D_MODEL + h*128 + d0 + ch*8];
  }
  __syncthreads();
  #pragma unroll
  for (int j = 0; j < 16; ++j){
    const int idx = t + 256*j;
    const int r = idx >> 6, c = idx & 63;
    vt[((size_t)bh*128 + d0 + r) * SEQ + s0 + c] = tile[c][r];
  }
}

// ---------------------------------------------------------------------------
// RoPE cos/sin tables: [SEQ][64] f32 each.
// ---------------------------------------------------------------------------
__global__ __launch_bounds__(256) void rope_table_kernel(float* __restrict__ ct,
                                                         float* __restrict__ st){
  const int i = blockIdx.x * 256 + threadIdx.x;
  if (i >= SEQ * 64) return;
  const int s = i >> 6, j = i & 63;
  const float inv = powf(10000.0f, -(float)j / 64.0f);
  const double a = (double)s * (double)inv;
  ct[i] = (float)cos(a);
  st[i] = (float)sin(a);
}

// ---------------------------------------------------------------------------
// In-place RoPE on bf16 buffer [ROWS][D_MODEL] viewed as [ROWS][H][128].
// ---------------------------------------------------------------------------
__global__ __launch_bounds__(256) void rope_apply(unsigned short* __restrict__ buf,
    const float* __restrict__ ct, const float* __restrict__ st, float scale){
  const int i = blockIdx.x * 256 + threadIdx.x;
  const int j = i & 63;
  const int tmp = i >> 6;
  const int h = tmp & 31;
  const int row = tmp >> 5;
  const int s = row & (SEQ - 1);
  const float c = ct[s*64 + j], sn = st[s*64 + j];
  const size_t base = (size_t)row * D_MODEL + (size_t)h * 128;
  const float x1 = bf2f(buf[base + j]);
  const float x2 = bf2f(buf[base + j + 64]);
  buf[base + j]      = f2bf((x1 * c - x2 * sn) * scale);
  buf[base + j + 64] = f2bf((x2 * c + x1 * sn) * scale);
}

// ---------------------------------------------------------------------------
// 128x128 m97-structure GEMM (kept for small-N latent projection).
// ---------------------------------------------------------------------------
template<bool OF32>
__global__ __launch_bounds__(256) void gemm_kernel(
    const unsigned short* __restrict__ A, const unsigned short* __restrict__ Bt,
    void* __restrict__ Cp, int M, int N, int K){
  __shared__ __align__(16) char As[128 * 128];
  __shared__ __align__(16) char Bs[128 * 128];
  const int t = threadIdx.x;
  const int m0 = blockIdx.y * 128, n0 = blockIdx.x * 128;
  const int l = t & 63, wid = t >> 6;
  const int wr = wid >> 1, wcn = wid & 1;
  const int lr = l & 15, lg = l >> 4;

  const int srow = l >> 3;
  const int gch  = (l & 7) ^ srow;
  const unsigned short* gA = A  + (size_t)(m0 + wid*32 + srow) * K + gch*8;
  const unsigned short* gB = Bt + (size_t)(n0 + wid*32 + srow) * K + gch*8;
  char* lA = As + wid*4096;
  char* lB = Bs + wid*4096;

  f32x4 acc[4][4];
  #pragma unroll
  for (int i = 0; i < 4; ++i)
    #pragma unroll
    for (int j = 0; j < 4; ++j)
      #pragma unroll
      for (int r = 0; r < 4; ++r) acc[i][j][r] = 0.0f;

  const int kTiles = K >> 6;
  for (int kt = 0; kt < kTiles; ++kt){
    const size_t ko = (size_t)kt << 6;
    #pragma unroll
    for (int i = 0; i < 4; ++i){
      gload16(gA + (size_t)i*8*K + ko, lA + i*1024);
      gload16(gB + (size_t)i*8*K + ko, lB + i*1024);
    }
    __syncthreads();
    #pragma unroll
    for (int kc = 0; kc < 2; ++kc){
      bf16x8 af[4], bfv[4];
      const int ch = kc*4 + lg;
      #pragma unroll
      for (int mb = 0; mb < 4; ++mb){
        const int row = wr*64 + mb*16 + lr;
        af[mb] = *(const bf16x8*)(As + row*128 + ((ch ^ (row & 7)) * 16));
      }
      #pragma unroll
      for (int nb = 0; nb < 4; ++nb){
        const int row = wcn*64 + nb*16 + lr;
        bfv[nb] = *(const bf16x8*)(Bs + row*128 + ((ch ^ (row & 7)) * 16));
      }
      #pragma unroll
      for (int mb = 0; mb < 4; ++mb)
        #pragma unroll
        for (int nb = 0; nb < 4; ++nb)
          acc[mb][nb] = __builtin_amdgcn_mfma_f32_16x16x32_bf16(af[mb], bfv[nb], acc[mb][nb], 0, 0, 0);
    }
    __syncthreads();
  }
  #pragma unroll
  for (int mb = 0; mb < 4; ++mb)
    #pragma unroll
    for (int nb = 0; nb < 4; ++nb)
      #pragma unroll
      for (int r = 0; r < 4; ++r){
        const int row = m0 + wr*64 + mb*16 + lg*4 + r;
        const int col = n0 + wcn*64 + nb*16 + lr;
        if constexpr (OF32) ((float*)Cp)[(size_t)row * N + col] = acc[mb][nb][r];
        else ((unsigned short*)Cp)[(size_t)row * N + col] = f2bf(acc[mb][nb][r]);
      }
}

// ---------------------------------------------------------------------------
// 256x256 8-phase GEMM (T2+T3+T4+T5), unchanged from R4.
// ---------------------------------------------------------------------------
template<int MH>
static __device__ __forceinline__ void rdAh(bf16x8 (&a_)[4][2], const char* buf,
                                            int wr, int lr, int lg){
  #pragma unroll
  for (int mm = 0; mm < 4; ++mm)
    #pragma unroll
    for (int kc = 0; kc < 2; ++kc){
      const int row = wr*128 + (MH*4 + mm)*16 + lr;
      const int ch = kc*4 + lg;
      a_[mm][kc] = *(const bf16x8*)(buf + row*128 + ((ch ^ (row & 7)) * 16));
    }
}
template<int NH>
static __device__ __forceinline__ void rdBh(bf16x8 (&b_)[2][2][2], const char* buf,
                                            int wc, int lr, int lg){
  #pragma unroll
  for (int nn = 0; nn < 2; ++nn)
    #pragma unroll
    for (int kc = 0; kc < 2; ++kc){
      const int row = wc*64 + (NH*2 + nn)*16 + lr;
      const int ch = kc*4 + lg;
      b_[NH][nn][kc] = *(const bf16x8*)(buf + row*128 + ((ch ^ (row & 7)) * 16));
    }
}
template<int MH, int NH>
static __device__ __forceinline__ void mfq(f32x4 (&acc)[8][4],
    const bf16x8 (&a_)[4][2], const bf16x8 (&b_)[2][2][2]){
  __builtin_amdgcn_s_setprio(1);
  #pragma unroll
  for (int kc = 0; kc < 2; ++kc)
    #pragma unroll
    for (int mm = 0; mm < 4; ++mm)
      #pragma unroll
      for (int nn = 0; nn < 2; ++nn)
        acc[MH*4+mm][NH*2+nn] = __builtin_amdgcn_mfma_f32_16x16x32_bf16(
            a_[mm][kc], b_[NH][nn][kc], acc[MH*4+mm][NH*2+nn], 0, 0, 0);
  __builtin_amdgcn_s_setprio(0);
}

#define G256_BAR  __builtin_amdgcn_s_barrier()
#define G256_LGK0 do{ asm volatile("s_waitcnt lgkmcnt(0)" ::: "memory"); \
                      __builtin_amdgcn_sched_barrier(0); }while(0)
#define G256_VM(n) asm volatile("s_waitcnt vmcnt(" #n ")" ::: "memory")

template<bool OF32>
__global__ __launch_bounds__(512, 2) void gemm256_kernel(
    const unsigned short* __restrict__ A, const unsigned short* __restrict__ Bt,
    void* __restrict__ Cp, int M, int N, int K){
  __shared__ __align__(16) char lds[131072];
  char* const As0 = lds;
  char* const As1 = lds + 32768;
  char* const Bs0 = lds + 65536;
  char* const Bs1 = lds + 98304;

  const int t = threadIdx.x;
  const int l = t & 63, wid = t >> 6;
  const int wr = wid >> 2, wc = wid & 3;
  const int lr = l & 15, lg = l >> 4;
  const int m0 = blockIdx.y * 256, n0 = blockIdx.x * 256;

  const int srow = t >> 3;
  const int pch = t & 7;
  const int gch = pch ^ (srow & 7);
  const unsigned short* gAb = A  + (size_t)(m0 + srow) * K + gch*8;
  const unsigned short* gBb = Bt + (size_t)(n0 + srow) * K + gch*8;
  const int ldso = srow*128 + pch*16;

  auto stA = [&](char* dst, int half, int kcol){
    const unsigned short* g = gAb + (size_t)half*128*K + kcol;
    gload16(g,                dst + half*16384 + ldso);
    gload16(g + (size_t)64*K, dst + half*16384 + 8192 + ldso);
  };
  auto stB = [&](char* dst, int half, int kcol){
    const unsigned short* g = gBb + (size_t)half*128*K + kcol;
    gload16(g,                dst + half*16384 + ldso);
    gload16(g + (size_t)64*K, dst + half*16384 + 8192 + ldso);
  };

  f32x4 acc[8][4];
  #pragma unroll
  for (int m = 0; m < 8; ++m)
    #pragma unroll
    for (int n = 0; n < 4; ++n)
      #pragma unroll
      for (int r = 0; r < 4; ++r) acc[m][n][r] = 0.0f;
  bf16x8 a_[4][2];
  bf16x8 b_[2][2][2];

  const int niter = K >> 7;
  stA(As0, 0, 0); stA(As0, 1, 0); stB(Bs0, 0, 0); stB(Bs0, 1, 0);
  stA(As1, 0, 64);
  G256_VM(2);
  G256_BAR;
  __builtin_amdgcn_sched_barrier(0);

  for (int j = 0; j < niter; ++j){
    const int k0 = j << 7;
    const bool more = (j + 1 < niter);
    rdAh<0>(a_, As0, wr, lr, lg);
    rdBh<0>(b_, Bs0, wc, lr, lg);
    stA(As1, 1, k0 + 64);
    G256_BAR; G256_LGK0;
    mfq<0,0>(acc, a_, b_);
    G256_BAR;
    rdBh<1>(b_, Bs0, wc, lr, lg);
    stB(Bs1, 0, k0 + 64);
    G256_BAR; G256_LGK0;
    mfq<0,1>(acc, a_, b_);
    G256_BAR;
    rdAh<1>(a_, As0, wr, lr, lg);
    stB(Bs1, 1, k0 + 64);
    G256_BAR; G256_LGK0;
    mfq<1,0>(acc, a_, b_);
    G256_BAR;
    if (more){ stA(As0, 0, k0 + 128); G256_VM(2); }
    else     { G256_VM(0); }
    G256_BAR;
    __builtin_amdgcn_sched_barrier(0);
    mfq<1,1>(acc, a_, b_);
    G256_BAR;
    rdAh<0>(a_, As1, wr, lr, lg);
    rdBh<0>(b_, Bs1, wc, lr, lg);
    if (more) stA(As0, 1, k0 + 128);
    G256_BAR; G256_LGK0;
    mfq<0,0>(acc, a_, b_);
    G256_BAR;
    rdBh<1>(b_, Bs1, wc, lr, lg);
    if (more) stB(Bs0, 0, k0 + 128);
    G256_BAR; G256_LGK0;
    mfq<0,1>(acc, a_, b_);
    G256_BAR;
    rdAh<1>(a_, As1, wr, lr, lg);
    if (more) stB(Bs0, 1, k0 + 128);
    G256_BAR; G256_LGK0;
    mfq<1,0>(acc, a_, b_);
    G256_BAR;
    if (more){ stA(As1, 0, k0 + 192); G256_VM(2); }
    G256_BAR;
    __builtin_amdgcn_sched_barrier(0);
    mfq<1,1>(acc, a_, b_);
    G256_BAR;
  }

  #pragma unroll
  for (int m = 0; m < 8; ++m)
    #pragma unroll
    for (int n = 0; n < 4; ++n)
      #pragma unroll
      for (int r = 0; r < 4; ++r){
        const int row = m0 + wr*128 + m*16 + lg*4 + r;
        const int col = n0 + wc*64 + n*16 + lr;
        if constexpr (OF32) ((float*)Cp)[(size_t)row * N + col] = acc[m][n][r];
        else ((unsigned short*)Cp)[(size_t)row * N + col] = f2bf(acc[m][n][r]);
      }
}

// ---------------------------------------------------------------------------
// Flash attention, 8 waves x 32 q-rows, KVBLK=64, 32x32x16 MFMA.
// R5: gload_lds staging (inverse-swizzled global source, linear LDS dest),
// double-buffered K/V (64 KiB), counted vmcnt(4) + raw barriers (prefetch
// survives across tiles), exp2-domain softmax (log2e folded into Q),
// v_cvt_pk_bf16_f32 P-repack, setprio around MFMA clusters.
// Scores arrive pre-scaled by (1/sqrt(Dh))*log2(e).
// ---------------------------------------------------------------------------
__global__ __launch_bounds__(512) void attn_kernel(
    const unsigned short* __restrict__ q, const unsigned short* __restrict__ kp,
    const unsigned short* __restrict__ vt, unsigned short* __restrict__ o){
  __shared__ __align__(16) char Ks[2 * 16384];
  __shared__ __align__(16) char Vs[2 * 16384];
  const int t = threadIdx.x;
  const int l = t & 63, w = t >> 6;
  const int lq = l & 31, hi = l >> 5;
  const int bh = blockIdx.x, qb = blockIdx.y;   // bh-major for XCD/L2 locality
  const int b = bh >> 5;
  const size_t qbase = (size_t)b * SEQ + qb*256 + w*32;
  const size_t cb = (size_t)(bh & 31) * 128;

  // stage: wave w covers K rows [w*8,w*8+8) (2 issues x 4 rows x 16 chunks)
  // and V^T rows [w*16,w*16+16) (2 issues x 8 rows x 8 chunks). LDS dest is
  // wave-uniform; per-lane global chunk is inverse-XOR-swizzled.
  auto stageKV = [&](int buf, int kb){
    const size_t kr0 = (size_t)b * SEQ + (size_t)kb*64;
    char* kdst = Ks + buf*16384 + w*2048;
    char* vdst = Vs + buf*16384 + w*2048;
    #pragma unroll
    for (int i = 0; i < 2; ++i){
      const int r = w*8 + i*4 + (l >> 4);
      const int g = (l & 15) ^ (r & 7);
      gload16(kp + (kr0 + r) * D_MODEL + cb + g*8, kdst + i*1024);
    }
    #pragma unroll
    for (int i = 0; i < 2; ++i){
      const int r = w*16 + i*8 + (l >> 3);
      const int g = (l & 7) ^ (r & 7);
      gload16(vt + ((size_t)bh*128 + r) * SEQ + (size_t)kb*64 + g*8, vdst + i*1024);
    }
  };

  bf16x8 qf[8];
  #pragma unroll
  for (int dc = 0; dc < 8; ++dc)
    qf[dc] = *(const bf16x8*)(q + (qbase + lq) * D_MODEL + cb + dc*16 + hi*8);

  f32x16 O[4];
  #pragma unroll
  for (int nb = 0; nb < 4; ++nb)
    #pragma unroll
    for (int r = 0; r < 16; ++r) O[nb][r] = 0.0f;
  float m = -1e30f, lsum = 0.0f;

  stageKV(0, 0);
  int cur = 0;
  for (int kb = 0; kb < SEQ/64; ++kb){
    const bool more = (kb + 1 < SEQ/64);
    if (more){
      stageKV(cur ^ 1, kb + 1);
      asm volatile("s_waitcnt vmcnt(4)" ::: "memory");
    } else {
      asm volatile("s_waitcnt vmcnt(0)" ::: "memory");
    }
    __builtin_amdgcn_s_barrier();
    __builtin_amdgcn_sched_barrier(0);
    const char* Kb = Ks + cur*16384;
    const char* Vb = Vs + cur*16384;

    // S^T = K * Q^T (scores in log2 domain)
    f32x16 s0, s1;
    #pragma unroll
    for (int r = 0; r < 16; ++r){ s0[r] = 0.0f; s1[r] = 0.0f; }
    __builtin_amdgcn_s_setprio(1);
    #pragma unroll
    for (int dc = 0; dc < 8; ++dc){
      const int ch = dc*2 + hi;
      const bf16x8 k0 = *(const bf16x8*)(Kb + lq*256 + ((ch ^ (lq & 7)) * 16));
      const bf16x8 k1 = *(const bf16x8*)(Kb + (32 + lq)*256 + ((ch ^ (lq & 7)) * 16));
      s0 = __builtin_amdgcn_mfma_f32_32x32x16_bf16(k0, qf[dc], s0, 0, 0, 0);
      s1 = __builtin_amdgcn_mfma_f32_32x32x16_bf16(k1, qf[dc], s1, 0, 0, 0);
    }
    __builtin_amdgcn_s_setprio(0);

    float mt = s0[0];
    #pragma unroll
    for (int r = 1; r < 16; ++r) mt = fmaxf(mt, s0[r]);
    #pragma unroll
    for (int r = 0; r < 16; ++r) mt = fmaxf(mt, s1[r]);
    mt = fmaxf(mt, __shfl_xor(mt, 32));

    if (!__all(mt <= m + 8.0f)){
      const float mnew = fmaxf(m, mt);
      const float al = __builtin_amdgcn_exp2f(m - mnew);
      m = mnew;
      lsum *= al;
      float alb[16];
      #pragma unroll
      for (int r = 0; r < 16; ++r){
        const int crow = (r & 3) + 8*(r >> 2) + 4*hi;
        alb[r] = __shfl(al, crow);
      }
      #pragma unroll
      for (int nb = 0; nb < 4; ++nb)
        #pragma unroll
        for (int r = 0; r < 16; ++r) O[nb][r] *= alb[r];
    }

    float E[32];
    float sum = 0.0f;
    #pragma unroll
    for (int r = 0; r < 16; ++r){ E[r] = __builtin_amdgcn_exp2f(s0[r] - m); sum += E[r]; }
    #pragma unroll
    for (int r = 0; r < 16; ++r){ E[16 + r] = __builtin_amdgcn_exp2f(s1[r] - m); sum += E[16 + r]; }
    sum += __shfl_xor(sum, 32);
    lsum += sum;

    bf16x8 pa[4];
    #pragma unroll
    for (int c = 0; c < 4; ++c){
      const int rb = c * 8;
      const uint a_ = cvtpk(E[rb + 0], E[rb + 1]);
      const uint b_ = cvtpk(E[rb + 2], E[rb + 3]);
      const uint c_ = cvtpk(E[rb + 4], E[rb + 5]);
      const uint d_ = cvtpk(E[rb + 6], E[rb + 7]);
      const uint sa = (uint)__shfl_xor((int)a_, 32);
      const uint sb = (uint)__shfl_xor((int)b_, 32);
      const uint sc = (uint)__shfl_xor((int)c_, 32);
      const uint sd = (uint)__shfl_xor((int)d_, 32);
      union { uint u[4]; bf16x8 v; } uu;
      uu.u[0] = hi ? sc : a_;
      uu.u[1] = hi ? sd : b_;
      uu.u[2] = hi ? c_ : sa;
      uu.u[3] = hi ? d_ : sb;
      pa[c] = uu.v;
    }

    __builtin_amdgcn_s_setprio(1);
    #pragma unroll
    for (int c = 0; c < 4; ++c){
      const int ch = c*2 + hi;
      #pragma unroll
      for (int nb = 0; nb < 4; ++nb){
        const int vr = nb*32 + lq;
        const bf16x8 vf = *(const bf16x8*)(Vb + vr*128 + ((ch ^ (vr & 7)) * 16));
        O[nb] = __builtin_amdgcn_mfma_f32_32x32x16_bf16(pa[c], vf, O[nb], 0, 0, 0);
      }
    }
    __builtin_amdgcn_s_setprio(0);
    __builtin_amdgcn_s_barrier();
    __builtin_amdgcn_sched_barrier(0);
    cur ^= 1;
  }

  const float rinv = 1.0f / lsum;
  float rb_[16];
  #pragma unroll
  for (int r = 0; r < 16; ++r){
    const int crow = (r & 3) + 8*(r >> 2) + 4*hi;
    rb_[r] = __shfl(rinv, crow);
  }
  #pragma unroll
  for (int nb = 0; nb < 4; ++nb)
    #pragma unroll
    for (int r = 0; r < 16; ++r){
      const int crow = (r & 3) + 8*(r >> 2) + 4*hi;
      o[(qbase + crow) * D_MODEL + cb + nb*32 + lq] = f2bf(O[nb][r] * rb_[r]);
    }
}

// ---------------------------------------------------------------------------
extern "C" void kernel_launch(void* const* d_in, const int* in_sizes, int n_in,
                              void* d_out, int out_size, void* d_ws, size_t ws_size,
                              hipStream_t stream){
  const float* hidden = (const float*)d_in[0];
  const float* Wq = (const float*)d_in[1];
  const float* Wc = (const float*)d_in[2];
  const float* Wk = (const float*)d_in[3];
  const float* Wv = (const float*)d_in[4];
  const float* Wo = (const float*)d_in[5];
  float* out = (float*)d_out;

  char* ws = (char*)d_ws;
  size_t off = 0;
  auto alloc = [&](size_t bytes)->char*{
    char* p = ws + off; off += (bytes + 255) & ~(size_t)255; return p;
  };
  unsigned short* Wqt  = (unsigned short*)alloc((size_t)D_MODEL * D_MODEL * 2);
  unsigned short* Wct  = (unsigned short*)alloc((size_t)D_LATENT * D_MODEL * 2);
  unsigned short* Wkt  = (unsigned short*)alloc((size_t)D_MODEL * D_LATENT * 2);
  unsigned short* Wvt  = (unsigned short*)alloc((size_t)D_MODEL * D_LATENT * 2);
  unsigned short* Wot  = (unsigned short*)alloc((size_t)D_MODEL * D_MODEL * 2);
  unsigned short* latent = (unsigned short*)alloc((size_t)ROWS * D_LATENT * 2);
  unsigned short* qbuf = (unsigned short*)alloc((size_t)ROWS * D_MODEL * 2);
  unsigned short* kbuf = (unsigned short*)alloc((size_t)ROWS * D_MODEL * 2);
  unsigned short* vbuf = (unsigned short*)alloc((size_t)ROWS * D_MODEL * 2);
  unsigned short* attnb= (unsigned short*)alloc((size_t)ROWS * D_MODEL * 2);
  float* ctab = (float*)alloc((size_t)SEQ * 64 * 4);
  float* stab = (float*)alloc((size_t)SEQ * 64 * 4);
  unsigned short* hbf   = attnb;  // alias: dead until attention writes it
  unsigned short* vtbuf = Wqt;    // alias: dead after Q-proj

  const dim3 B256(256);
  // 1/sqrt(128) * log2(e): scores come out in log2 domain for exp2 softmax
  const float qscale = 0.08838834764831845f * 1.4426950408889634f;

  f32_to_bf16<<<(ROWS*(size_t)D_MODEL)/2048, B256, 0, stream>>>(hidden, hbf);
  transpose_convert<<<dim3(64, 64), B256, 0, stream>>>(Wq, Wqt, D_MODEL, D_MODEL);
  transpose_convert<<<dim3(64, 8),  B256, 0, stream>>>(Wc, Wct, D_MODEL, D_LATENT);
  transpose_convert<<<dim3(8, 64),  B256, 0, stream>>>(Wk, Wkt, D_LATENT, D_MODEL);
  transpose_convert<<<dim3(8, 64),  B256, 0, stream>>>(Wv, Wvt, D_LATENT, D_MODEL);
  transpose_convert<<<dim3(64, 64), B256, 0, stream>>>(Wo, Wot, D_MODEL, D_MODEL);
  rope_table_kernel<<<512, B256, 0, stream>>>(ctab, stab);

  // projections
  gemm_kernel<false><<<dim3(D_LATENT/128, ROWS/128), B256, 0, stream>>>(hbf, Wct, latent, ROWS, D_LATENT, D_MODEL);
  gemm256_kernel<false><<<dim3(D_MODEL/256, ROWS/256), dim3(512), 0, stream>>>(hbf,    Wqt, qbuf, ROWS, D_MODEL, D_MODEL);
  gemm256_kernel<false><<<dim3(D_MODEL/256, ROWS/256), dim3(512), 0, stream>>>(latent, Wkt, kbuf, ROWS, D_MODEL, D_LATENT);
  gemm256_kernel<false><<<dim3(D_MODEL/256, ROWS/256), dim3(512), 0, stream>>>(latent, Wvt, vbuf, ROWS, D_MODEL, D_LATENT);

  // V^T (overwrites Wqt region — dead now)
  v_transpose<<<dim3(SEQ/64, HEAD_DIM/64, BATCH*NUM_HEADS), B256, 0, stream>>>(vbuf, vtbuf);

  // RoPE (1/sqrt(Dh)*log2e folded into Q)
  rope_apply<<<(ROWS * NUM_HEADS * 64) / 256, B256, 0, stream>>>(qbuf, ctab, stab, qscale);
  rope_apply<<<(ROWS * NUM_HEADS * 64) / 256, B256, 0, stream>>>(kbuf, ctab, stab, 1.0f);

  // attention (bh-major grid: 8 q-blocks of one head land on one XCD)
  attn_kernel<<<dim3(BATCH * NUM_HEADS, SEQ/256), dim3(512), 0, stream>>>(qbuf, kbuf, vtbuf, attnb);

  // output projection (f32 out)
  gemm256_kernel<true><<<dim3(D_MODEL/256, ROWS/256), dim3(512), 0, stream>>>(attnb, Wot, out, ROWS, D_MODEL, D_MODEL);
}